// Round 1
// baseline (8500.465 us; speedup 1.0000x reference)
//
#include <hip/hip_runtime.h>
#include <math.h>

// ---------------------------------------------------------------------------
// MultiViewEPSSClassifier forward: proj+LN+GELU -> 4x(GatedGraphConv x4) ->
// per-view LN+residual -> attention fusion -> mean/max pool -> MLP.
// All fp32. N=50000, E=600000, IN=512, H=128, B=64, L=4.
// ---------------------------------------------------------------------------

__device__ __forceinline__ float sigmoidf_(float x) { return 1.0f / (1.0f + expf(-x)); }

__device__ __forceinline__ void atomicMaxF(float* addr, float v) {
    if (v >= 0.0f) atomicMax((int*)addr, __float_as_int(v));
    else           atomicMin((unsigned int*)addr, __float_as_uint(v));
}

// ------------------------- GEMM: C = A @ B (+bias) -------------------------
// A: [N,K] row-major. BT=false: B is [K,M] row-major. BT=true: B is [M,K]
// row-major and we compute A @ B^T. Tile 128x128, BK=32, 8x8 per thread
// (2x2 blocks of 4x4 to keep LDS reads conflict-free). EPI: 0 none, 1 tanh.
template <bool BT, int EPI>
__global__ __launch_bounds__(256, 2) void gemm_k(
    const float* __restrict__ A, const float* __restrict__ Bm,
    const float* __restrict__ bias, float* __restrict__ C,
    int N, int M, int K, long sA, long sB, long sC)
{
    __shared__ float As[32][132];
    __shared__ float Bs[32][132];
    A  += (long)blockIdx.z * sA;
    Bm += (long)blockIdx.z * sB;
    C  += (long)blockIdx.z * sC;
    const int r0 = blockIdx.x * 128;
    const int c0 = blockIdx.y * 128;
    const int tid = threadIdx.x;
    const int tx = tid & 15;   // col group
    const int ty = tid >> 4;   // row group

    float acc[8][8];
#pragma unroll
    for (int i = 0; i < 8; i++)
#pragma unroll
        for (int j = 0; j < 8; j++) acc[i][j] = 0.0f;

    for (int k0 = 0; k0 < K; k0 += 32) {
        {   // A tile: 128 rows x 32 k, stored k-major (transposed)
            int arow = tid >> 3;
            int akq  = (tid & 7) << 2;
#pragma unroll
            for (int hh = 0; hh < 4; hh++) {
                int r  = arow + hh * 32;
                int gr = r0 + r;
                float4 av = make_float4(0.f, 0.f, 0.f, 0.f);
                if (gr < N) av = *(const float4*)(A + (long)gr * K + k0 + akq);
                As[akq + 0][r] = av.x; As[akq + 1][r] = av.y;
                As[akq + 2][r] = av.z; As[akq + 3][r] = av.w;
            }
        }
        if (BT) {
            int brow = tid >> 3;
            int bkq  = (tid & 7) << 2;
#pragma unroll
            for (int hh = 0; hh < 4; hh++) {
                int r = brow + hh * 32;   // m index within tile
                float4 bv = *(const float4*)(Bm + (long)(c0 + r) * K + k0 + bkq);
                Bs[bkq + 0][r] = bv.x; Bs[bkq + 1][r] = bv.y;
                Bs[bkq + 2][r] = bv.z; Bs[bkq + 3][r] = bv.w;
            }
        } else {
            int kk0 = tid >> 5;          // 0..7
            int bmq = (tid & 31) << 2;   // 0..124
#pragma unroll
            for (int hh = 0; hh < 4; hh++) {
                int kk = kk0 + hh * 8;
                float4 bv = *(const float4*)(Bm + (long)(k0 + kk) * M + c0 + bmq);
                *(float4*)&Bs[kk][bmq] = bv;
            }
        }
        __syncthreads();
#pragma unroll
        for (int k = 0; k < 32; k++) {
            float4 a0 = *(const float4*)&As[k][ty << 2];
            float4 a1 = *(const float4*)&As[k][64 + (ty << 2)];
            float4 b0 = *(const float4*)&Bs[k][tx << 2];
            float4 b1 = *(const float4*)&Bs[k][64 + (tx << 2)];
            float av[8] = {a0.x, a0.y, a0.z, a0.w, a1.x, a1.y, a1.z, a1.w};
            float bv[8] = {b0.x, b0.y, b0.z, b0.w, b1.x, b1.y, b1.z, b1.w};
#pragma unroll
            for (int i = 0; i < 8; i++)
#pragma unroll
                for (int j = 0; j < 8; j++) acc[i][j] += av[i] * bv[j];
        }
        __syncthreads();
    }

    float bb[8] = {0, 0, 0, 0, 0, 0, 0, 0};
    if (bias) {
        float4 b0 = *(const float4*)(bias + c0 + (tx << 2));
        float4 b1 = *(const float4*)(bias + c0 + 64 + (tx << 2));
        bb[0] = b0.x; bb[1] = b0.y; bb[2] = b0.z; bb[3] = b0.w;
        bb[4] = b1.x; bb[5] = b1.y; bb[6] = b1.z; bb[7] = b1.w;
    }
#pragma unroll
    for (int i = 0; i < 8; i++) {
        int r = (i < 4) ? (r0 + (ty << 2) + i) : (r0 + 64 + (ty << 2) + i - 4);
        if (r < N) {
            float v[8];
#pragma unroll
            for (int j = 0; j < 8; j++) {
                v[j] = acc[i][j] + bb[j];
                if (EPI == 1) v[j] = tanhf(v[j]);
            }
            float4 c0v = make_float4(v[0], v[1], v[2], v[3]);
            float4 c1v = make_float4(v[4], v[5], v[6], v[7]);
            *(float4*)(C + (long)r * M + c0 + (tx << 2)) = c0v;
            *(float4*)(C + (long)r * M + c0 + 64 + (tx << 2)) = c1v;
        }
    }
}

// ----------------------- LayerNorm + GELU (in-place) -----------------------
__global__ __launch_bounds__(256) void ln_gelu_k(
    float* __restrict__ h0, const float* __restrict__ w, const float* __restrict__ b, int N)
{
    long t = (long)blockIdx.x * 256 + threadIdx.x;
    int n = (int)(t >> 5), lane = (int)(t & 31);
    if (n >= N) return;
    float* p = h0 + (long)n * 128 + lane * 4;
    float4 x = *(float4*)p;
    float s = x.x + x.y + x.z + x.w;
#pragma unroll
    for (int off = 16; off >= 1; off >>= 1) s += __shfl_xor(s, off);
    float mu = s * (1.0f / 128.0f);
    float4 d = make_float4(x.x - mu, x.y - mu, x.z - mu, x.w - mu);
    float ss = d.x * d.x + d.y * d.y + d.z * d.z + d.w * d.w;
#pragma unroll
    for (int off = 16; off >= 1; off >>= 1) ss += __shfl_xor(ss, off);
    float inv = 1.0f / sqrtf(ss * (1.0f / 128.0f) + 1e-5f);
    float4 wv = *(const float4*)(w + lane * 4);
    float4 bv = *(const float4*)(b + lane * 4);
    float y[4] = {d.x * inv * wv.x + bv.x, d.y * inv * wv.y + bv.y,
                  d.z * inv * wv.z + bv.z, d.w * inv * wv.w + bv.w};
#pragma unroll
    for (int i = 0; i < 4; i++)
        y[i] = 0.5f * y[i] * (1.0f + erff(y[i] * 0.70710678118654752f));
    *(float4*)p = make_float4(y[0], y[1], y[2], y[3]);
}

// --------------------------- broadcast h0 -> h[4] --------------------------
__global__ __launch_bounds__(256) void bcast4_k(
    const float4* __restrict__ src, float4* __restrict__ dst, long n4)
{
    long t = (long)blockIdx.x * 256 + threadIdx.x;
    if (t < n4) {
        float4 v = src[t];
        dst[t] = v; dst[n4 + t] = v; dst[2 * n4 + t] = v; dst[3 * n4 + t] = v;
    }
}

// ------------------- masked scatter-add over edges (all views) -------------
__global__ __launch_bounds__(256) void scatter_k(
    const float* __restrict__ m, float* __restrict__ agg,
    const int* __restrict__ src, const int* __restrict__ dst,
    const int* __restrict__ et, int E, int N)
{
    long t = (long)blockIdx.x * 256 + threadIdx.x;
    int e = (int)(t >> 5), lane = (int)(t & 31);
    if (e >= E) return;
    int ty_ = et[e];
    // types {0,9,10}->0, {1,2,3}->1, {4,5,6}->2, {7,8,11,12}->3
    int v = (ty_ >= 1 && ty_ <= 3) ? 1 : (ty_ >= 4 && ty_ <= 6) ? 2
          : ((ty_ == 7) || (ty_ == 8) || (ty_ >= 11)) ? 3 : 0;
    long sidx = ((long)v * N + src[e]) * 128 + lane * 4;
    long didx = ((long)v * N + dst[e]) * 128 + lane * 4;
    float4 mv = *(const float4*)(m + sidx);
    float* ap = agg + didx;
    atomicAdd(ap + 0, mv.x); atomicAdd(ap + 1, mv.y);
    atomicAdd(ap + 2, mv.z); atomicAdd(ap + 3, mv.w);
}

// ------------------------------- GRU gates ---------------------------------
__global__ __launch_bounds__(256) void gru_gate_k(
    const float* __restrict__ gi, const float* __restrict__ gh,
    float* __restrict__ h, int N)
{
    long t = (long)blockIdx.x * 256 + threadIdx.x;
    int n = (int)(t >> 5), lane = (int)(t & 31);
    if (n >= N) return;
    const float* gip = gi + (long)n * 384 + lane * 4;
    const float* ghp = gh + (long)n * 384 + lane * 4;
    float4 ir = *(const float4*)(gip);
    float4 iz = *(const float4*)(gip + 128);
    float4 in_ = *(const float4*)(gip + 256);
    float4 hr = *(const float4*)(ghp);
    float4 hz = *(const float4*)(ghp + 128);
    float4 hn = *(const float4*)(ghp + 256);
    float* hp = h + (long)n * 128 + lane * 4;
    float4 hc = *(float4*)hp;
    float r[4] = {sigmoidf_(ir.x + hr.x), sigmoidf_(ir.y + hr.y),
                  sigmoidf_(ir.z + hr.z), sigmoidf_(ir.w + hr.w)};
    float z[4] = {sigmoidf_(iz.x + hz.x), sigmoidf_(iz.y + hz.y),
                  sigmoidf_(iz.z + hz.z), sigmoidf_(iz.w + hz.w)};
    float nn[4] = {tanhf(in_.x + r[0] * hn.x), tanhf(in_.y + r[1] * hn.y),
                   tanhf(in_.z + r[2] * hn.z), tanhf(in_.w + r[3] * hn.w)};
    float hv[4] = {hc.x, hc.y, hc.z, hc.w};
    float o[4];
#pragma unroll
    for (int i = 0; i < 4; i++) o[i] = (1.0f - z[i]) * nn[i] + z[i] * hv[i];
    *(float4*)hp = make_float4(o[0], o[1], o[2], o[3]);
}

// -------------------- per-view LayerNorm + residual (in-place) -------------
__global__ __launch_bounds__(256) void vln_res_k(
    float* __restrict__ h, const float* __restrict__ h0,
    const float* __restrict__ w, const float* __restrict__ b, int N)
{
    int v = blockIdx.z;
    long t = (long)blockIdx.x * 256 + threadIdx.x;
    int n = (int)(t >> 5), lane = (int)(t & 31);
    if (n >= N) return;
    float* hp = h + ((long)v * N + n) * 128 + lane * 4;
    float4 x = *(float4*)hp;
    float s = x.x + x.y + x.z + x.w;
#pragma unroll
    for (int off = 16; off >= 1; off >>= 1) s += __shfl_xor(s, off);
    float mu = s * (1.0f / 128.0f);
    float4 d = make_float4(x.x - mu, x.y - mu, x.z - mu, x.w - mu);
    float ss = d.x * d.x + d.y * d.y + d.z * d.z + d.w * d.w;
#pragma unroll
    for (int off = 16; off >= 1; off >>= 1) ss += __shfl_xor(ss, off);
    float inv = 1.0f / sqrtf(ss * (1.0f / 128.0f) + 1e-5f);
    float4 wv = *(const float4*)(w + v * 128 + lane * 4);
    float4 bv = *(const float4*)(b + v * 128 + lane * 4);
    float4 hv = *(const float4*)(h0 + (long)n * 128 + lane * 4);
    float4 r;
    r.x = d.x * inv * wv.x + bv.x + hv.x;
    r.y = d.y * inv * wv.y + bv.y + hv.y;
    r.z = d.z * inv * wv.z + bv.z + hv.z;
    r.w = d.w * inv * wv.w + bv.w + hv.w;
    *(float4*)hp = r;
}

// --------------------------- pooling buffers init --------------------------
__global__ __launch_bounds__(256) void pool_init_k(
    float* __restrict__ meanb, float* __restrict__ maxb, float* __restrict__ cntb)
{
    int t = blockIdx.x * 256 + threadIdx.x;
    if (t < 64 * 128) { meanb[t] = 0.0f; maxb[t] = __int_as_float(0xff800000); }
    if (t < 64) cntb[t] = 0.0f;
}

// -------------- attention fusion + mean/max pooling (atomics) --------------
__global__ __launch_bounds__(256) void fusion_pool_k(
    const float* __restrict__ hs, const float* __restrict__ q,
    const float* __restrict__ u, const float* __restrict__ kb,
    const int* __restrict__ batch, float* __restrict__ meanb,
    float* __restrict__ maxb, float* __restrict__ cntb, int N)
{
    long t = (long)blockIdx.x * 256 + threadIdx.x;
    int n = (int)(t >> 5), lane = (int)(t & 31);
    if (n >= N) return;
    long NH = (long)N * 128;
    float4 qv = *(const float4*)(q + (long)n * 128 + lane * 4);
    float4 kv = *(const float4*)(kb + lane * 4);
    float4 uv = *(const float4*)(u + (long)n * 128 + lane * 4);
    float part = qv.x * kv.x + qv.y * kv.y + qv.z * kv.z + qv.w * kv.w;
    float4 hv[4];
    float lg[4];
#pragma unroll
    for (int v = 0; v < 4; v++) {
        hv[v] = *(const float4*)(hs + v * NH + (long)n * 128 + lane * 4);
        lg[v] = hv[v].x * uv.x + hv[v].y * uv.y + hv[v].z * uv.z + hv[v].w * uv.w;
    }
#pragma unroll
    for (int off = 16; off >= 1; off >>= 1) {
        part += __shfl_xor(part, off);
#pragma unroll
        for (int v = 0; v < 4; v++) lg[v] += __shfl_xor(lg[v], off);
    }
    const float scale = 0.08838834764831845f;  // 128^-0.5
    float mx = -1e30f;
#pragma unroll
    for (int v = 0; v < 4; v++) { lg[v] = (lg[v] + part) * scale; mx = fmaxf(mx, lg[v]); }
    float se = 0.0f;
#pragma unroll
    for (int v = 0; v < 4; v++) { lg[v] = expf(lg[v] - mx); se += lg[v]; }
    float inv = 1.0f / se;
    float4 f = make_float4(0.f, 0.f, 0.f, 0.f);
#pragma unroll
    for (int v = 0; v < 4; v++) {
        float a = lg[v] * inv;
        f.x += a * hv[v].x; f.y += a * hv[v].y; f.z += a * hv[v].z; f.w += a * hv[v].w;
    }
    int b = batch[n];
    float* mp = meanb + b * 128 + lane * 4;
    atomicAdd(mp + 0, f.x); atomicAdd(mp + 1, f.y);
    atomicAdd(mp + 2, f.z); atomicAdd(mp + 3, f.w);
    float* xp = maxb + b * 128 + lane * 4;
    atomicMaxF(xp + 0, f.x); atomicMaxF(xp + 1, f.y);
    atomicMaxF(xp + 2, f.z); atomicMaxF(xp + 3, f.w);
    if (lane == 0) atomicAdd(cntb + b, 1.0f);
}

// ------------------------------ classifier MLP -----------------------------
__global__ __launch_bounds__(256) void classifier_k(
    const float* __restrict__ meanb, const float* __restrict__ maxb,
    const float* __restrict__ cntb,
    const float* __restrict__ c1w, const float* __restrict__ c1b,
    const float* __restrict__ c2w, const float* __restrict__ c2b,
    const float* __restrict__ c3w, const float* __restrict__ c3b,
    float* __restrict__ out)
{
    __shared__ float sm[16384];  // 64 KiB
    int tid = threadIdx.x;
    for (int i = tid; i < 64 * 256; i += 256) {
        int b = i >> 8, k = i & 255;
        float v;
        if (k < 128) {
            float c = fmaxf(cntb[b], 1.0f);
            v = meanb[b * 128 + k] / c;
        } else v = maxb[b * 128 + (k - 128)];
        sm[i] = v;
    }
    __syncthreads();
    // h1[64][128]
    float r1[32];
    {
        int b = tid >> 2;
        int m0 = (tid & 3) * 32;
#pragma unroll
        for (int j = 0; j < 32; j++) r1[j] = c1b[m0 + j];
        for (int k = 0; k < 256; k++) {
            float gv = sm[b * 256 + k];
            const float* wr = c1w + k * 128 + m0;
#pragma unroll
            for (int j = 0; j < 32; j++) r1[j] += gv * wr[j];
        }
#pragma unroll
        for (int j = 0; j < 32; j++) r1[j] = fmaxf(r1[j], 0.0f);
    }
    __syncthreads();
    {
        int b = tid >> 2; int m0 = (tid & 3) * 32;
#pragma unroll
        for (int j = 0; j < 32; j++) sm[b * 128 + m0 + j] = r1[j];
    }
    __syncthreads();
    // h2[64][64]
    float r2[16];
    {
        int b = tid >> 2; int m0 = (tid & 3) * 16;
#pragma unroll
        for (int j = 0; j < 16; j++) r2[j] = c2b[m0 + j];
        for (int k = 0; k < 128; k++) {
            float hvv = sm[b * 128 + k];
            const float* wr = c2w + k * 64 + m0;
#pragma unroll
            for (int j = 0; j < 16; j++) r2[j] += hvv * wr[j];
        }
#pragma unroll
        for (int j = 0; j < 16; j++) r2[j] = fmaxf(r2[j], 0.0f);
    }
    __syncthreads();
    {
        int b = tid >> 2; int m0 = (tid & 3) * 16;
#pragma unroll
        for (int j = 0; j < 16; j++) sm[8192 + b * 64 + m0 + j] = r2[j];
    }
    __syncthreads();
    if (tid < 64) {
        float acc = c3b[0];
        for (int j = 0; j < 64; j++) acc += sm[8192 + tid * 64 + j] * c3w[j];
        out[tid] = acc;
    }
}

// ---------------------------------------------------------------------------
extern "C" void kernel_launch(void* const* d_in, const int* in_sizes, int n_in,
                              void* d_out, int out_size, void* d_ws, size_t ws_size,
                              hipStream_t stream) {
    (void)n_in; (void)out_size; (void)ws_size;
    const float* x      = (const float*)d_in[0];
    const int*   eidx   = (const int*)d_in[1];
    const int*   etype  = (const int*)d_in[2];
    const int*   batch  = (const int*)d_in[3];
    const float* proj_w = (const float*)d_in[4];
    const float* proj_b = (const float*)d_in[5];
    const float* ln0_w  = (const float*)d_in[6];
    const float* ln0_b  = (const float*)d_in[7];
    const float* ggnn_w = (const float*)d_in[8];
    const float* gwih   = (const float*)d_in[9];
    const float* gwhh   = (const float*)d_in[10];
    const float* gbih   = (const float*)d_in[11];
    const float* gbhh   = (const float*)d_in[12];
    const float* vln_w  = (const float*)d_in[13];
    const float* vln_b  = (const float*)d_in[14];
    const float* q_w    = (const float*)d_in[15];
    const float* q_b    = (const float*)d_in[16];
    const float* k_w    = (const float*)d_in[17];
    const float* k_b    = (const float*)d_in[18];
    const float* c1w    = (const float*)d_in[19];
    const float* c1b    = (const float*)d_in[20];
    const float* c2w    = (const float*)d_in[21];
    const float* c2b    = (const float*)d_in[22];
    const float* c3w    = (const float*)d_in[23];
    const float* c3b    = (const float*)d_in[24];
    float* out = (float*)d_out;

    const int N = in_sizes[3];
    const int E = in_sizes[2];
    const int IN = in_sizes[0] / N;
    const int H = 128, L = 4;

    long NH = (long)N * H;
    float* ws  = (float*)d_ws;
    float* h0  = ws;                 // NH
    float* h   = h0 + NH;            // 4*NH  (per-view hidden / hs after vln)
    float* agg = h + 4 * NH;         // 4*NH
    float* scr = agg + 4 * NH;       // 6*NH  (m[4]; later gi+gh; later q+u)
    float* poolMean = scr + 6 * NH;  // 64*128
    float* poolMax  = poolMean + 64 * H;
    float* poolCnt  = poolMax + 64 * H;  // 64

    int gx = (N + 127) / 128;
    int rb = (int)(((long)N * 32 + 255) / 256);

    // 1. input projection: h0 = x @ proj_w + proj_b
    gemm_k<false, 0><<<dim3(gx, 1, 1), 256, 0, stream>>>(
        x, proj_w, proj_b, h0, N, H, IN, 0, 0, 0);
    // 2. LayerNorm + GELU in-place
    ln_gelu_k<<<rb, 256, 0, stream>>>(h0, ln0_w, ln0_b, N);
    // 3. broadcast h0 into 4 view states
    bcast4_k<<<(int)((NH / 4 + 255) / 256), 256, 0, stream>>>(
        (const float4*)h0, (float4*)h, NH / 4);

    for (int i = 0; i < L; i++) {
        // m[v] = h[v] @ ggnn_w[v][i]   (batched over views via grid.z)
        gemm_k<false, 0><<<dim3(gx, 1, 4), 256, 0, stream>>>(
            h, ggnn_w + (long)i * H * H, nullptr, scr,
            N, H, H, NH, (long)L * H * H, NH);
        hipMemsetAsync(agg, 0, (size_t)(4 * NH * sizeof(float)), stream);
        scatter_k<<<(int)(((long)E * 32 + 255) / 256), 256, 0, stream>>>(
            scr, agg, eidx, eidx + E, etype, E, N);
        for (int v = 0; v < 4; v++) {
            float* gi = scr;                   // N*384
            float* gh = scr + (long)N * 384;   // N*384
            gemm_k<true, 0><<<dim3(gx, 3, 1), 256, 0, stream>>>(
                agg + (long)v * NH, gwih + (long)v * 384 * H, gbih + v * 384,
                gi, N, 384, H, 0, 0, 0);
            gemm_k<true, 0><<<dim3(gx, 3, 1), 256, 0, stream>>>(
                h + (long)v * NH, gwhh + (long)v * 384 * H, gbhh + v * 384,
                gh, N, 384, H, 0, 0, 0);
            gru_gate_k<<<rb, 256, 0, stream>>>(gi, gh, h + (long)v * NH, N);
        }
    }

    // per-view LN + residual (h becomes hs)
    vln_res_k<<<dim3(rb, 1, 4), 256, 0, stream>>>(h, h0, vln_w, vln_b, N);

    // attention: q = tanh(h0@q_w + q_b); u = q @ k_w^T
    float* q = scr;
    float* u = scr + NH;
    gemm_k<false, 1><<<dim3(gx, 1, 1), 256, 0, stream>>>(
        h0, q_w, q_b, q, N, H, H, 0, 0, 0);
    gemm_k<true, 0><<<dim3(gx, 1, 1), 256, 0, stream>>>(
        q, k_w, nullptr, u, N, H, H, 0, 0, 0);

    pool_init_k<<<32, 256, 0, stream>>>(poolMean, poolMax, poolCnt);
    fusion_pool_k<<<rb, 256, 0, stream>>>(
        h, q, u, k_b, batch, poolMean, poolMax, poolCnt, N);
    classifier_k<<<1, 256, 0, stream>>>(
        poolMean, poolMax, poolCnt, c1w, c1b, c2w, c2b, c3w, c3b, out);
}

// Round 2
// 4918.274 us; speedup vs baseline: 1.7283x; 1.7283x over previous
//
#include <hip/hip_runtime.h>
#include <math.h>

// ---------------------------------------------------------------------------
// MultiViewEPSSClassifier forward: proj+LN+GELU -> 4x(GatedGraphConv x4) ->
// per-view LN+residual -> attention fusion -> mean/max pool -> MLP.
// All fp32. N=50000, E=600000, IN=512, H=128, B=64, L=4.
// R2: atomic scatter -> CSR gather (bucket sort by view*N+dst, built once).
// ---------------------------------------------------------------------------

__device__ __forceinline__ float sigmoidf_(float x) { return 1.0f / (1.0f + expf(-x)); }

__device__ __forceinline__ void atomicMaxF(float* addr, float v) {
    if (v >= 0.0f) atomicMax((int*)addr, __float_as_int(v));
    else           atomicMin((unsigned int*)addr, __float_as_uint(v));
}

// types {0,9,10}->0, {1,2,3}->1, {4,5,6}->2, {7,8,11,12}->3 (partition of 0..12)
__device__ __forceinline__ int view_of(int t) {
    return (t >= 1 && t <= 3) ? 1 : (t >= 4 && t <= 6) ? 2
         : ((t == 7) || (t == 8) || (t >= 11)) ? 3 : 0;
}

// ------------------------- GEMM: C = A @ B (+bias) -------------------------
// A: [N,K] row-major. BT=false: B is [K,M] row-major. BT=true: B is [M,K]
// row-major and we compute A @ B^T. Tile 128x128, BK=32, 8x8 per thread
// (2x2 blocks of 4x4 to keep LDS reads conflict-free). EPI: 0 none, 1 tanh.
template <bool BT, int EPI>
__global__ __launch_bounds__(256, 2) void gemm_k(
    const float* __restrict__ A, const float* __restrict__ Bm,
    const float* __restrict__ bias, float* __restrict__ C,
    int N, int M, int K, long sA, long sB, long sC)
{
    __shared__ float As[32][132];
    __shared__ float Bs[32][132];
    A  += (long)blockIdx.z * sA;
    Bm += (long)blockIdx.z * sB;
    C  += (long)blockIdx.z * sC;
    const int r0 = blockIdx.x * 128;
    const int c0 = blockIdx.y * 128;
    const int tid = threadIdx.x;
    const int tx = tid & 15;   // col group
    const int ty = tid >> 4;   // row group

    float acc[8][8];
#pragma unroll
    for (int i = 0; i < 8; i++)
#pragma unroll
        for (int j = 0; j < 8; j++) acc[i][j] = 0.0f;

    for (int k0 = 0; k0 < K; k0 += 32) {
        {   // A tile: 128 rows x 32 k, stored k-major (transposed)
            int arow = tid >> 3;
            int akq  = (tid & 7) << 2;
#pragma unroll
            for (int hh = 0; hh < 4; hh++) {
                int r  = arow + hh * 32;
                int gr = r0 + r;
                float4 av = make_float4(0.f, 0.f, 0.f, 0.f);
                if (gr < N) av = *(const float4*)(A + (long)gr * K + k0 + akq);
                As[akq + 0][r] = av.x; As[akq + 1][r] = av.y;
                As[akq + 2][r] = av.z; As[akq + 3][r] = av.w;
            }
        }
        if (BT) {
            int brow = tid >> 3;
            int bkq  = (tid & 7) << 2;
#pragma unroll
            for (int hh = 0; hh < 4; hh++) {
                int r = brow + hh * 32;   // m index within tile
                float4 bv = *(const float4*)(Bm + (long)(c0 + r) * K + k0 + bkq);
                Bs[bkq + 0][r] = bv.x; Bs[bkq + 1][r] = bv.y;
                Bs[bkq + 2][r] = bv.z; Bs[bkq + 3][r] = bv.w;
            }
        } else {
            int kk0 = tid >> 5;          // 0..7
            int bmq = (tid & 31) << 2;   // 0..124
#pragma unroll
            for (int hh = 0; hh < 4; hh++) {
                int kk = kk0 + hh * 8;
                float4 bv = *(const float4*)(Bm + (long)(k0 + kk) * M + c0 + bmq);
                *(float4*)&Bs[kk][bmq] = bv;
            }
        }
        __syncthreads();
#pragma unroll
        for (int k = 0; k < 32; k++) {
            float4 a0 = *(const float4*)&As[k][ty << 2];
            float4 a1 = *(const float4*)&As[k][64 + (ty << 2)];
            float4 b0 = *(const float4*)&Bs[k][tx << 2];
            float4 b1 = *(const float4*)&Bs[k][64 + (tx << 2)];
            float av[8] = {a0.x, a0.y, a0.z, a0.w, a1.x, a1.y, a1.z, a1.w};
            float bv[8] = {b0.x, b0.y, b0.z, b0.w, b1.x, b1.y, b1.z, b1.w};
#pragma unroll
            for (int i = 0; i < 8; i++)
#pragma unroll
                for (int j = 0; j < 8; j++) acc[i][j] += av[i] * bv[j];
        }
        __syncthreads();
    }

    float bb[8] = {0, 0, 0, 0, 0, 0, 0, 0};
    if (bias) {
        float4 b0 = *(const float4*)(bias + c0 + (tx << 2));
        float4 b1 = *(const float4*)(bias + c0 + 64 + (tx << 2));
        bb[0] = b0.x; bb[1] = b0.y; bb[2] = b0.z; bb[3] = b0.w;
        bb[4] = b1.x; bb[5] = b1.y; bb[6] = b1.z; bb[7] = b1.w;
    }
#pragma unroll
    for (int i = 0; i < 8; i++) {
        int r = (i < 4) ? (r0 + (ty << 2) + i) : (r0 + 64 + (ty << 2) + i - 4);
        if (r < N) {
            float v[8];
#pragma unroll
            for (int j = 0; j < 8; j++) {
                v[j] = acc[i][j] + bb[j];
                if (EPI == 1) v[j] = tanhf(v[j]);
            }
            float4 c0v = make_float4(v[0], v[1], v[2], v[3]);
            float4 c1v = make_float4(v[4], v[5], v[6], v[7]);
            *(float4*)(C + (long)r * M + c0 + (tx << 2)) = c0v;
            *(float4*)(C + (long)r * M + c0 + 64 + (tx << 2)) = c1v;
        }
    }
}

// ----------------------- LayerNorm + GELU (in-place) -----------------------
__global__ __launch_bounds__(256) void ln_gelu_k(
    float* __restrict__ h0, const float* __restrict__ w, const float* __restrict__ b, int N)
{
    long t = (long)blockIdx.x * 256 + threadIdx.x;
    int n = (int)(t >> 5), lane = (int)(t & 31);
    if (n >= N) return;
    float* p = h0 + (long)n * 128 + lane * 4;
    float4 x = *(float4*)p;
    float s = x.x + x.y + x.z + x.w;
#pragma unroll
    for (int off = 16; off >= 1; off >>= 1) s += __shfl_xor(s, off);
    float mu = s * (1.0f / 128.0f);
    float4 d = make_float4(x.x - mu, x.y - mu, x.z - mu, x.w - mu);
    float ss = d.x * d.x + d.y * d.y + d.z * d.z + d.w * d.w;
#pragma unroll
    for (int off = 16; off >= 1; off >>= 1) ss += __shfl_xor(ss, off);
    float inv = 1.0f / sqrtf(ss * (1.0f / 128.0f) + 1e-5f);
    float4 wv = *(const float4*)(w + lane * 4);
    float4 bv = *(const float4*)(b + lane * 4);
    float y[4] = {d.x * inv * wv.x + bv.x, d.y * inv * wv.y + bv.y,
                  d.z * inv * wv.z + bv.z, d.w * inv * wv.w + bv.w};
#pragma unroll
    for (int i = 0; i < 4; i++)
        y[i] = 0.5f * y[i] * (1.0f + erff(y[i] * 0.70710678118654752f));
    *(float4*)p = make_float4(y[0], y[1], y[2], y[3]);
}

// --------------------------- broadcast h0 -> h[4] --------------------------
__global__ __launch_bounds__(256) void bcast4_k(
    const float4* __restrict__ src, float4* __restrict__ dst, long n4)
{
    long t = (long)blockIdx.x * 256 + threadIdx.x;
    if (t < n4) {
        float4 v = src[t];
        dst[t] = v; dst[n4 + t] = v; dst[2 * n4 + t] = v; dst[3 * n4 + t] = v;
    }
}

// ------------------------------ CSR build ----------------------------------
__global__ __launch_bounds__(256) void count_k(
    const int* __restrict__ dst, const int* __restrict__ et,
    int* __restrict__ cnt, int E, int N)
{
    int e = blockIdx.x * 256 + threadIdx.x;
    if (e >= E) return;
    int v = view_of(et[e]);
    atomicAdd(&cnt[v * N + dst[e]], 1);
}

// block scans 1024 elements (256 thr x 4); writes per-element exclusive
// (within block) to off, block total to bsum.
__global__ __launch_bounds__(256) void scan1_k(
    const int* __restrict__ cnt, int* __restrict__ off, int* __restrict__ bsum, int n)
{
    __shared__ int sm[256];
    int base = blockIdx.x * 1024;
    int tid = threadIdx.x;
    int v[4]; int s = 0;
#pragma unroll
    for (int i = 0; i < 4; i++) {
        int idx = base + tid * 4 + i;
        v[i] = (idx < n) ? cnt[idx] : 0; s += v[i];
    }
    sm[tid] = s; __syncthreads();
    for (int o = 1; o < 256; o <<= 1) {
        int t2 = (tid >= o) ? sm[tid - o] : 0;
        __syncthreads(); sm[tid] += t2; __syncthreads();
    }
    int run = sm[tid] - s;   // exclusive within block
    if (tid == 255) bsum[blockIdx.x] = sm[255];
#pragma unroll
    for (int i = 0; i < 4; i++) {
        int idx = base + tid * 4 + i;
        if (idx < n) off[idx] = run;
        run += v[i];
    }
}

__global__ __launch_bounds__(256) void scan2_k(int* __restrict__ bsum, int nb)
{
    __shared__ int sm[256];
    int tid = threadIdx.x;
    int v = (tid < nb) ? bsum[tid] : 0;
    sm[tid] = v; __syncthreads();
    for (int o = 1; o < 256; o <<= 1) {
        int t2 = (tid >= o) ? sm[tid - o] : 0;
        __syncthreads(); sm[tid] += t2; __syncthreads();
    }
    if (tid < nb) bsum[tid] = sm[tid] - v;   // exclusive
}

__global__ __launch_bounds__(256) void scan3_k(
    int* __restrict__ off, int* __restrict__ cursor,
    const int* __restrict__ bsum, int n, int total)
{
    int i = blockIdx.x * 256 + threadIdx.x;
    if (i < n) {
        int o = off[i] + bsum[i >> 10];
        off[i] = o; cursor[i] = o;
    }
    if (i == 0) off[n] = total;
}

__global__ __launch_bounds__(256) void fill_k(
    const int* __restrict__ src, const int* __restrict__ dst,
    const int* __restrict__ et, int* __restrict__ cursor,
    int* __restrict__ esrc, int E, int N)
{
    int e = blockIdx.x * 256 + threadIdx.x;
    if (e >= E) return;
    int v = view_of(et[e]);
    int b = v * N + dst[e];
    int pos = atomicAdd(&cursor[b], 1);
    esrc[pos] = v * N + src[e];   // full m-row index
}

// -------------------- CSR gather: agg[r] = sum m[esrc[j]] ------------------
__global__ __launch_bounds__(256) void gather_k(
    const float* __restrict__ m, float* __restrict__ agg,
    const int* __restrict__ off, const int* __restrict__ esrc, int R)
{
    long t = (long)blockIdx.x * 256 + threadIdx.x;
    int r = (int)(t >> 5), lane = (int)(t & 31);
    if (r >= R) return;
    int beg = off[r], end = off[r + 1];
    float4 acc = make_float4(0.f, 0.f, 0.f, 0.f);
    for (int j = beg; j < end; j++) {
        int s = esrc[j];
        float4 mv = *(const float4*)(m + (long)s * 128 + lane * 4);
        acc.x += mv.x; acc.y += mv.y; acc.z += mv.z; acc.w += mv.w;
    }
    *(float4*)(agg + (long)r * 128 + lane * 4) = acc;
}

// ------------------------------- GRU gates ---------------------------------
__global__ __launch_bounds__(256) void gru_gate_k(
    const float* __restrict__ gi, const float* __restrict__ gh,
    float* __restrict__ h, int N)
{
    long t = (long)blockIdx.x * 256 + threadIdx.x;
    int n = (int)(t >> 5), lane = (int)(t & 31);
    if (n >= N) return;
    const float* gip = gi + (long)n * 384 + lane * 4;
    const float* ghp = gh + (long)n * 384 + lane * 4;
    float4 ir = *(const float4*)(gip);
    float4 iz = *(const float4*)(gip + 128);
    float4 in_ = *(const float4*)(gip + 256);
    float4 hr = *(const float4*)(ghp);
    float4 hz = *(const float4*)(ghp + 128);
    float4 hn = *(const float4*)(ghp + 256);
    float* hp = h + (long)n * 128 + lane * 4;
    float4 hc = *(float4*)hp;
    float r[4] = {sigmoidf_(ir.x + hr.x), sigmoidf_(ir.y + hr.y),
                  sigmoidf_(ir.z + hr.z), sigmoidf_(ir.w + hr.w)};
    float z[4] = {sigmoidf_(iz.x + hz.x), sigmoidf_(iz.y + hz.y),
                  sigmoidf_(iz.z + hz.z), sigmoidf_(iz.w + hz.w)};
    float nn[4] = {tanhf(in_.x + r[0] * hn.x), tanhf(in_.y + r[1] * hn.y),
                   tanhf(in_.z + r[2] * hn.z), tanhf(in_.w + r[3] * hn.w)};
    float hv[4] = {hc.x, hc.y, hc.z, hc.w};
    float o[4];
#pragma unroll
    for (int i = 0; i < 4; i++) o[i] = (1.0f - z[i]) * nn[i] + z[i] * hv[i];
    *(float4*)hp = make_float4(o[0], o[1], o[2], o[3]);
}

// -------------------- per-view LayerNorm + residual (in-place) -------------
__global__ __launch_bounds__(256) void vln_res_k(
    float* __restrict__ h, const float* __restrict__ h0,
    const float* __restrict__ w, const float* __restrict__ b, int N)
{
    int v = blockIdx.z;
    long t = (long)blockIdx.x * 256 + threadIdx.x;
    int n = (int)(t >> 5), lane = (int)(t & 31);
    if (n >= N) return;
    float* hp = h + ((long)v * N + n) * 128 + lane * 4;
    float4 x = *(float4*)hp;
    float s = x.x + x.y + x.z + x.w;
#pragma unroll
    for (int off = 16; off >= 1; off >>= 1) s += __shfl_xor(s, off);
    float mu = s * (1.0f / 128.0f);
    float4 d = make_float4(x.x - mu, x.y - mu, x.z - mu, x.w - mu);
    float ss = d.x * d.x + d.y * d.y + d.z * d.z + d.w * d.w;
#pragma unroll
    for (int off = 16; off >= 1; off >>= 1) ss += __shfl_xor(ss, off);
    float inv = 1.0f / sqrtf(ss * (1.0f / 128.0f) + 1e-5f);
    float4 wv = *(const float4*)(w + v * 128 + lane * 4);
    float4 bv = *(const float4*)(b + v * 128 + lane * 4);
    float4 hv = *(const float4*)(h0 + (long)n * 128 + lane * 4);
    float4 r;
    r.x = d.x * inv * wv.x + bv.x + hv.x;
    r.y = d.y * inv * wv.y + bv.y + hv.y;
    r.z = d.z * inv * wv.z + bv.z + hv.z;
    r.w = d.w * inv * wv.w + bv.w + hv.w;
    *(float4*)hp = r;
}

// --------------------------- pooling buffers init --------------------------
__global__ __launch_bounds__(256) void pool_init_k(
    float* __restrict__ meanb, float* __restrict__ maxb, float* __restrict__ cntb)
{
    int t = blockIdx.x * 256 + threadIdx.x;
    if (t < 64 * 128) { meanb[t] = 0.0f; maxb[t] = __int_as_float(0xff800000); }
    if (t < 64) cntb[t] = 0.0f;
}

// -------------- attention fusion + mean/max pooling (atomics) --------------
__global__ __launch_bounds__(256) void fusion_pool_k(
    const float* __restrict__ hs, const float* __restrict__ q,
    const float* __restrict__ u, const float* __restrict__ kb,
    const int* __restrict__ batch, float* __restrict__ meanb,
    float* __restrict__ maxb, float* __restrict__ cntb, int N)
{
    long t = (long)blockIdx.x * 256 + threadIdx.x;
    int n = (int)(t >> 5), lane = (int)(t & 31);
    if (n >= N) return;
    long NH = (long)N * 128;
    float4 qv = *(const float4*)(q + (long)n * 128 + lane * 4);
    float4 kv = *(const float4*)(kb + lane * 4);
    float4 uv = *(const float4*)(u + (long)n * 128 + lane * 4);
    float part = qv.x * kv.x + qv.y * kv.y + qv.z * kv.z + qv.w * kv.w;
    float4 hv[4];
    float lg[4];
#pragma unroll
    for (int v = 0; v < 4; v++) {
        hv[v] = *(const float4*)(hs + v * NH + (long)n * 128 + lane * 4);
        lg[v] = hv[v].x * uv.x + hv[v].y * uv.y + hv[v].z * uv.z + hv[v].w * uv.w;
    }
#pragma unroll
    for (int off = 16; off >= 1; off >>= 1) {
        part += __shfl_xor(part, off);
#pragma unroll
        for (int v = 0; v < 4; v++) lg[v] += __shfl_xor(lg[v], off);
    }
    const float scale = 0.08838834764831845f;  // 128^-0.5
    float mx = -1e30f;
#pragma unroll
    for (int v = 0; v < 4; v++) { lg[v] = (lg[v] + part) * scale; mx = fmaxf(mx, lg[v]); }
    float se = 0.0f;
#pragma unroll
    for (int v = 0; v < 4; v++) { lg[v] = expf(lg[v] - mx); se += lg[v]; }
    float inv = 1.0f / se;
    float4 f = make_float4(0.f, 0.f, 0.f, 0.f);
#pragma unroll
    for (int v = 0; v < 4; v++) {
        float a = lg[v] * inv;
        f.x += a * hv[v].x; f.y += a * hv[v].y; f.z += a * hv[v].z; f.w += a * hv[v].w;
    }
    int b = batch[n];
    float* mp = meanb + b * 128 + lane * 4;
    atomicAdd(mp + 0, f.x); atomicAdd(mp + 1, f.y);
    atomicAdd(mp + 2, f.z); atomicAdd(mp + 3, f.w);
    float* xp = maxb + b * 128 + lane * 4;
    atomicMaxF(xp + 0, f.x); atomicMaxF(xp + 1, f.y);
    atomicMaxF(xp + 2, f.z); atomicMaxF(xp + 3, f.w);
    if (lane == 0) atomicAdd(cntb + b, 1.0f);
}

// ------------------------------ classifier MLP -----------------------------
__global__ __launch_bounds__(256) void classifier_k(
    const float* __restrict__ meanb, const float* __restrict__ maxb,
    const float* __restrict__ cntb,
    const float* __restrict__ c1w, const float* __restrict__ c1b,
    const float* __restrict__ c2w, const float* __restrict__ c2b,
    const float* __restrict__ c3w, const float* __restrict__ c3b,
    float* __restrict__ out)
{
    __shared__ float sm[16384];  // 64 KiB
    int tid = threadIdx.x;
    for (int i = tid; i < 64 * 256; i += 256) {
        int b = i >> 8, k = i & 255;
        float v;
        if (k < 128) {
            float c = fmaxf(cntb[b], 1.0f);
            v = meanb[b * 128 + k] / c;
        } else v = maxb[b * 128 + (k - 128)];
        sm[i] = v;
    }
    __syncthreads();
    // h1[64][128]
    float r1[32];
    {
        int b = tid >> 2;
        int m0 = (tid & 3) * 32;
#pragma unroll
        for (int j = 0; j < 32; j++) r1[j] = c1b[m0 + j];
        for (int k = 0; k < 256; k++) {
            float gv = sm[b * 256 + k];
            const float* wr = c1w + k * 128 + m0;
#pragma unroll
            for (int j = 0; j < 32; j++) r1[j] += gv * wr[j];
        }
#pragma unroll
        for (int j = 0; j < 32; j++) r1[j] = fmaxf(r1[j], 0.0f);
    }
    __syncthreads();
    {
        int b = tid >> 2; int m0 = (tid & 3) * 32;
#pragma unroll
        for (int j = 0; j < 32; j++) sm[b * 128 + m0 + j] = r1[j];
    }
    __syncthreads();
    // h2[64][64]
    float r2[16];
    {
        int b = tid >> 2; int m0 = (tid & 3) * 16;
#pragma unroll
        for (int j = 0; j < 16; j++) r2[j] = c2b[m0 + j];
        for (int k = 0; k < 128; k++) {
            float hvv = sm[b * 128 + k];
            const float* wr = c2w + k * 64 + m0;
#pragma unroll
            for (int j = 0; j < 16; j++) r2[j] += hvv * wr[j];
        }
#pragma unroll
        for (int j = 0; j < 16; j++) r2[j] = fmaxf(r2[j], 0.0f);
    }
    __syncthreads();
    {
        int b = tid >> 2; int m0 = (tid & 3) * 16;
#pragma unroll
        for (int j = 0; j < 16; j++) sm[8192 + b * 64 + m0 + j] = r2[j];
    }
    __syncthreads();
    if (tid < 64) {
        float acc = c3b[0];
        for (int j = 0; j < 64; j++) acc += sm[8192 + tid * 64 + j] * c3w[j];
        out[tid] = acc;
    }
}

// ---------------------------------------------------------------------------
extern "C" void kernel_launch(void* const* d_in, const int* in_sizes, int n_in,
                              void* d_out, int out_size, void* d_ws, size_t ws_size,
                              hipStream_t stream) {
    (void)n_in; (void)out_size; (void)ws_size;
    const float* x      = (const float*)d_in[0];
    const int*   eidx   = (const int*)d_in[1];
    const int*   etype  = (const int*)d_in[2];
    const int*   batch  = (const int*)d_in[3];
    const float* proj_w = (const float*)d_in[4];
    const float* proj_b = (const float*)d_in[5];
    const float* ln0_w  = (const float*)d_in[6];
    const float* ln0_b  = (const float*)d_in[7];
    const float* ggnn_w = (const float*)d_in[8];
    const float* gwih   = (const float*)d_in[9];
    const float* gwhh   = (const float*)d_in[10];
    const float* gbih   = (const float*)d_in[11];
    const float* gbhh   = (const float*)d_in[12];
    const float* vln_w  = (const float*)d_in[13];
    const float* vln_b  = (const float*)d_in[14];
    const float* q_w    = (const float*)d_in[15];
    const float* q_b    = (const float*)d_in[16];
    const float* k_w    = (const float*)d_in[17];
    const float* k_b    = (const float*)d_in[18];
    const float* c1w    = (const float*)d_in[19];
    const float* c1b    = (const float*)d_in[20];
    const float* c2w    = (const float*)d_in[21];
    const float* c2b    = (const float*)d_in[22];
    const float* c3w    = (const float*)d_in[23];
    const float* c3b    = (const float*)d_in[24];
    float* out = (float*)d_out;

    const int N = in_sizes[3];
    const int E = in_sizes[2];
    const int IN = in_sizes[0] / N;
    const int H = 128, L = 4;
    const int N4 = 4 * N;

    long NH = (long)N * H;
    float* ws  = (float*)d_ws;
    float* h0  = ws;                 // NH
    float* h   = h0 + NH;            // 4*NH  (per-view hidden / hs after vln)
    float* agg = h + 4 * NH;         // 4*NH
    float* scr = agg + 4 * NH;       // 6*NH  (m[4]; later gi+gh; later q+u)
    float* poolMean = scr + 6 * NH;  // 64*128
    float* poolMax  = poolMean + 64 * H;
    float* poolCnt  = poolMax + 64 * H;  // 64
    // integer CSR buffers
    int* iOff  = (int*)(poolCnt + 64);   // N4+1
    int* iCnt  = iOff + N4 + 1;          // N4
    int* iCur  = iCnt + N4;              // N4
    int* iBsum = iCur + N4;              // 256
    int* iEsrc = iBsum + 256;            // E

    int gx = (N + 127) / 128;
    int rb = (int)(((long)N * 32 + 255) / 256);
    int eb = (E + 255) / 256;
    int nbScan = (N4 + 1023) / 1024;

    const int* esrc_in = eidx;
    const int* edst_in = eidx + E;

    // ---- CSR build (once per call; structure shared across layers) ----
    hipMemsetAsync(iCnt, 0, (size_t)N4 * sizeof(int), stream);
    count_k<<<eb, 256, 0, stream>>>(edst_in, etype, iCnt, E, N);
    scan1_k<<<nbScan, 256, 0, stream>>>(iCnt, iOff, iBsum, N4);
    scan2_k<<<1, 256, 0, stream>>>(iBsum, nbScan);
    scan3_k<<<(N4 + 255) / 256, 256, 0, stream>>>(iOff, iCur, iBsum, N4, E);
    fill_k<<<eb, 256, 0, stream>>>(esrc_in, edst_in, etype, iCur, iEsrc, E, N);

    // 1. input projection: h0 = x @ proj_w + proj_b
    gemm_k<false, 0><<<dim3(gx, 1, 1), 256, 0, stream>>>(
        x, proj_w, proj_b, h0, N, H, IN, 0, 0, 0);
    // 2. LayerNorm + GELU in-place
    ln_gelu_k<<<rb, 256, 0, stream>>>(h0, ln0_w, ln0_b, N);
    // 3. broadcast h0 into 4 view states
    bcast4_k<<<(int)((NH / 4 + 255) / 256), 256, 0, stream>>>(
        (const float4*)h0, (float4*)h, NH / 4);

    for (int i = 0; i < L; i++) {
        // m[v] = h[v] @ ggnn_w[v][i]   (batched over views via grid.z)
        gemm_k<false, 0><<<dim3(gx, 1, 4), 256, 0, stream>>>(
            h, ggnn_w + (long)i * H * H, nullptr, scr,
            N, H, H, NH, (long)L * H * H, NH);
        gather_k<<<(int)(((long)N4 * 32 + 255) / 256), 256, 0, stream>>>(
            scr, agg, iOff, iEsrc, N4);
        for (int v = 0; v < 4; v++) {
            float* gi = scr;                   // N*384
            float* gh = scr + (long)N * 384;   // N*384
            gemm_k<true, 0><<<dim3(gx, 3, 1), 256, 0, stream>>>(
                agg + (long)v * NH, gwih + (long)v * 384 * H, gbih + v * 384,
                gi, N, 384, H, 0, 0, 0);
            gemm_k<true, 0><<<dim3(gx, 3, 1), 256, 0, stream>>>(
                h + (long)v * NH, gwhh + (long)v * 384 * H, gbhh + v * 384,
                gh, N, 384, H, 0, 0, 0);
            gru_gate_k<<<rb, 256, 0, stream>>>(gi, gh, h + (long)v * NH, N);
        }
    }

    // per-view LN + residual (h becomes hs)
    vln_res_k<<<dim3(rb, 1, 4), 256, 0, stream>>>(h, h0, vln_w, vln_b, N);

    // attention: q = tanh(h0@q_w + q_b); u = q @ k_w^T
    float* q = scr;
    float* u = scr + NH;
    gemm_k<false, 1><<<dim3(gx, 1, 1), 256, 0, stream>>>(
        h0, q_w, q_b, q, N, H, H, 0, 0, 0);
    gemm_k<true, 0><<<dim3(gx, 1, 1), 256, 0, stream>>>(
        q, k_w, nullptr, u, N, H, H, 0, 0, 0);

    pool_init_k<<<32, 256, 0, stream>>>(poolMean, poolMax, poolCnt);
    fusion_pool_k<<<rb, 256, 0, stream>>>(
        h, q, u, k_b, batch, poolMean, poolMax, poolCnt, N);
    classifier_k<<<1, 256, 0, stream>>>(
        poolMean, poolMax, poolCnt, c1w, c1b, c2w, c2b, c3w, c3b, out);
}

// Round 3
// 4548.426 us; speedup vs baseline: 1.8689x; 1.0813x over previous
//
#include <hip/hip_runtime.h>
#include <math.h>

// ---------------------------------------------------------------------------
// MultiViewEPSSClassifier forward. All fp32. N=50000, E=600000, IN=512,
// H=128, B=64, L=4.
// R2: atomic scatter -> CSR gather.
// R3: (a) atomic-free fusion+pool (batch sorted -> one block per graph);
//     (b) GRU fused into one GEMM via repacked W' (channels x gates
//         interleaved), eliminating gi/gh round-trips and gru_gate_k.
// ---------------------------------------------------------------------------

__device__ __forceinline__ float sigmoidf_(float x) { return 1.0f / (1.0f + expf(-x)); }

// types {0,9,10}->0, {1,2,3}->1, {4,5,6}->2, {7,8,11,12}->3 (partition of 0..12)
__device__ __forceinline__ int view_of(int t) {
    return (t >= 1 && t <= 3) ? 1 : (t >= 4 && t <= 6) ? 2
         : ((t == 7) || (t == 8) || (t >= 11)) ? 3 : 0;
}

// ------------------------- GEMM: C = A @ B (+bias) -------------------------
// A: [N,K] row-major. BT=false: B is [K,M] row-major. BT=true: B is [M,K]
// row-major and we compute A @ B^T. Tile 128x128, BK=32, 8x8 per thread.
// EPI: 0 none, 1 tanh.
template <bool BT, int EPI>
__global__ __launch_bounds__(256, 2) void gemm_k(
    const float* __restrict__ A, const float* __restrict__ Bm,
    const float* __restrict__ bias, float* __restrict__ C,
    int N, int M, int K, long sA, long sB, long sC)
{
    __shared__ float As[32][132];
    __shared__ float Bs[32][132];
    A  += (long)blockIdx.z * sA;
    Bm += (long)blockIdx.z * sB;
    C  += (long)blockIdx.z * sC;
    const int r0 = blockIdx.x * 128;
    const int c0 = blockIdx.y * 128;
    const int tid = threadIdx.x;
    const int tx = tid & 15;   // col group
    const int ty = tid >> 4;   // row group

    float acc[8][8];
#pragma unroll
    for (int i = 0; i < 8; i++)
#pragma unroll
        for (int j = 0; j < 8; j++) acc[i][j] = 0.0f;

    for (int k0 = 0; k0 < K; k0 += 32) {
        {   // A tile: 128 rows x 32 k, stored k-major (transposed)
            int arow = tid >> 3;
            int akq  = (tid & 7) << 2;
#pragma unroll
            for (int hh = 0; hh < 4; hh++) {
                int r  = arow + hh * 32;
                int gr = r0 + r;
                float4 av = make_float4(0.f, 0.f, 0.f, 0.f);
                if (gr < N) av = *(const float4*)(A + (long)gr * K + k0 + akq);
                As[akq + 0][r] = av.x; As[akq + 1][r] = av.y;
                As[akq + 2][r] = av.z; As[akq + 3][r] = av.w;
            }
        }
        if (BT) {
            int brow = tid >> 3;
            int bkq  = (tid & 7) << 2;
#pragma unroll
            for (int hh = 0; hh < 4; hh++) {
                int r = brow + hh * 32;   // m index within tile
                float4 bv = *(const float4*)(Bm + (long)(c0 + r) * K + k0 + bkq);
                Bs[bkq + 0][r] = bv.x; Bs[bkq + 1][r] = bv.y;
                Bs[bkq + 2][r] = bv.z; Bs[bkq + 3][r] = bv.w;
            }
        } else {
            int kk0 = tid >> 5;          // 0..7
            int bmq = (tid & 31) << 2;   // 0..124
#pragma unroll
            for (int hh = 0; hh < 4; hh++) {
                int kk = kk0 + hh * 8;
                float4 bv = *(const float4*)(Bm + (long)(k0 + kk) * M + c0 + bmq);
                *(float4*)&Bs[kk][bmq] = bv;
            }
        }
        __syncthreads();
#pragma unroll
        for (int k = 0; k < 32; k++) {
            float4 a0 = *(const float4*)&As[k][ty << 2];
            float4 a1 = *(const float4*)&As[k][64 + (ty << 2)];
            float4 b0 = *(const float4*)&Bs[k][tx << 2];
            float4 b1 = *(const float4*)&Bs[k][64 + (tx << 2)];
            float av[8] = {a0.x, a0.y, a0.z, a0.w, a1.x, a1.y, a1.z, a1.w};
            float bv[8] = {b0.x, b0.y, b0.z, b0.w, b1.x, b1.y, b1.z, b1.w};
#pragma unroll
            for (int i = 0; i < 8; i++)
#pragma unroll
                for (int j = 0; j < 8; j++) acc[i][j] += av[i] * bv[j];
        }
        __syncthreads();
    }

    float bb[8] = {0, 0, 0, 0, 0, 0, 0, 0};
    if (bias) {
        float4 b0 = *(const float4*)(bias + c0 + (tx << 2));
        float4 b1 = *(const float4*)(bias + c0 + 64 + (tx << 2));
        bb[0] = b0.x; bb[1] = b0.y; bb[2] = b0.z; bb[3] = b0.w;
        bb[4] = b1.x; bb[5] = b1.y; bb[6] = b1.z; bb[7] = b1.w;
    }
#pragma unroll
    for (int i = 0; i < 8; i++) {
        int r = (i < 4) ? (r0 + (ty << 2) + i) : (r0 + 64 + (ty << 2) + i - 4);
        if (r < N) {
            float v[8];
#pragma unroll
            for (int j = 0; j < 8; j++) {
                v[j] = acc[i][j] + bb[j];
                if (EPI == 1) v[j] = tanhf(v[j]);
            }
            float4 c0v = make_float4(v[0], v[1], v[2], v[3]);
            float4 c1v = make_float4(v[4], v[5], v[6], v[7]);
            *(float4*)(C + (long)r * M + c0 + (tx << 2)) = c0v;
            *(float4*)(C + (long)r * M + c0 + 64 + (tx << 2)) = c1v;
        }
    }
}

// ---------------- build repacked GRU weights W'[4][256][512] ---------------
// col m = ch*4 + gate, gates: 0=rsum, 1=zsum, 2=inn(agg only), 3=hn(h only).
// row k: k<128 -> agg input (Wih), k>=128 -> h input (Whh).
__global__ __launch_bounds__(256) void build_wp_k(
    const float* __restrict__ gwih, const float* __restrict__ gwhh,
    const float* __restrict__ gbih, const float* __restrict__ gbhh,
    float* __restrict__ wp, float* __restrict__ bp)
{
    int idx = blockIdx.x * 256 + threadIdx.x;
    if (idx < 4 * 256 * 512) {
        int v = idx >> 17;           // / (256*512)
        int rem = idx & 131071;
        int k = rem >> 9;            // 0..255
        int m = rem & 511;
        int ch = m >> 2, gate = m & 3;
        const float* Wih = gwih + (long)v * 384 * 128;
        const float* Whh = gwhh + (long)v * 384 * 128;
        float val = 0.0f;
        if (gate == 0) val = (k < 128) ? Wih[ch * 128 + k] : Whh[ch * 128 + (k - 128)];
        else if (gate == 1) val = (k < 128) ? Wih[(128 + ch) * 128 + k] : Whh[(128 + ch) * 128 + (k - 128)];
        else if (gate == 2) val = (k < 128) ? Wih[(256 + ch) * 128 + k] : 0.0f;
        else val = (k < 128) ? 0.0f : Whh[(256 + ch) * 128 + (k - 128)];
        wp[idx] = val;
    }
    if (idx < 4 * 512) {
        int v = idx >> 9;
        int m = idx & 511;
        int ch = m >> 2, gate = m & 3;
        float val;
        if (gate == 0) val = gbih[v * 384 + ch] + gbhh[v * 384 + ch];
        else if (gate == 1) val = gbih[v * 384 + 128 + ch] + gbhh[v * 384 + 128 + ch];
        else if (gate == 2) val = gbih[v * 384 + 256 + ch];
        else val = gbhh[v * 384 + 256 + ch];
        bp[idx] = val;
    }
}

// ---------------- fused GRU GEMM: h_next = GRU(agg, h_cur) -----------------
// C-space: [N x 512] per view, K=256 over [agg|h]. grid (nx, 4, 4 views).
__global__ __launch_bounds__(256, 2) void gemm_gru_k(
    const float* __restrict__ agg, const float* __restrict__ hcur,
    const float* __restrict__ wp, const float* __restrict__ bp,
    float* __restrict__ hnext, int N, long sA)
{
    __shared__ float As[32][132];
    __shared__ float Bs[32][132];
    const int z = blockIdx.z;
    agg   += (long)z * sA;
    hcur  += (long)z * sA;
    wp    += (long)z * 256 * 512;
    bp    += (long)z * 512;
    hnext += (long)z * sA;
    const int r0 = blockIdx.x * 128;
    const int c0 = blockIdx.y * 128;
    const int tid = threadIdx.x;
    const int tx = tid & 15;
    const int ty = tid >> 4;

    float acc[8][8];
#pragma unroll
    for (int i = 0; i < 8; i++)
#pragma unroll
        for (int j = 0; j < 8; j++) acc[i][j] = 0.0f;

    for (int k0 = 0; k0 < 256; k0 += 32) {
        const float* Asrc = (k0 < 128) ? agg : hcur;
        int kcol = (k0 < 128) ? k0 : (k0 - 128);
        {
            int arow = tid >> 3;
            int akq  = (tid & 7) << 2;
#pragma unroll
            for (int hh = 0; hh < 4; hh++) {
                int r  = arow + hh * 32;
                int gr = r0 + r;
                float4 av = make_float4(0.f, 0.f, 0.f, 0.f);
                if (gr < N) av = *(const float4*)(Asrc + (long)gr * 128 + kcol + akq);
                As[akq + 0][r] = av.x; As[akq + 1][r] = av.y;
                As[akq + 2][r] = av.z; As[akq + 3][r] = av.w;
            }
        }
        {
            int kk0 = tid >> 5;          // 0..7
            int bmq = (tid & 31) << 2;   // 0..124
#pragma unroll
            for (int hh = 0; hh < 4; hh++) {
                int kk = kk0 + hh * 8;
                float4 bv = *(const float4*)(wp + (long)(k0 + kk) * 512 + c0 + bmq);
                *(float4*)&Bs[kk][bmq] = bv;
            }
        }
        __syncthreads();
#pragma unroll
        for (int k = 0; k < 32; k++) {
            float4 a0 = *(const float4*)&As[k][ty << 2];
            float4 a1 = *(const float4*)&As[k][64 + (ty << 2)];
            float4 b0 = *(const float4*)&Bs[k][tx << 2];
            float4 b1 = *(const float4*)&Bs[k][64 + (tx << 2)];
            float av[8] = {a0.x, a0.y, a0.z, a0.w, a1.x, a1.y, a1.z, a1.w};
            float bv[8] = {b0.x, b0.y, b0.z, b0.w, b1.x, b1.y, b1.z, b1.w};
#pragma unroll
            for (int i = 0; i < 8; i++)
#pragma unroll
                for (int j = 0; j < 8; j++) acc[i][j] += av[i] * bv[j];
        }
        __syncthreads();
    }

    float bb[8];
    {
        float4 b0 = *(const float4*)(bp + c0 + (tx << 2));
        float4 b1 = *(const float4*)(bp + c0 + 64 + (tx << 2));
        bb[0] = b0.x; bb[1] = b0.y; bb[2] = b0.z; bb[3] = b0.w;
        bb[4] = b1.x; bb[5] = b1.y; bb[6] = b1.z; bb[7] = b1.w;
    }
    // thread's 8 cols = 2 full channels x 4 gates (m = c0 + tx*4 + j, ch=m>>2)
    const int ch0 = (c0 >> 2) + tx;
    const int ch1 = ch0 + 16;
#pragma unroll
    for (int i = 0; i < 8; i++) {
        int r = (i < 4) ? (r0 + (ty << 2) + i) : (r0 + 64 + (ty << 2) + i - 4);
        if (r < N) {
            float hp0 = hcur[(long)r * 128 + ch0];
            float hp1 = hcur[(long)r * 128 + ch1];
            float rr0 = sigmoidf_(acc[i][0] + bb[0]);
            float zz0 = sigmoidf_(acc[i][1] + bb[1]);
            float nn0 = tanhf(acc[i][2] + bb[2] + rr0 * (acc[i][3] + bb[3]));
            float rr1 = sigmoidf_(acc[i][4] + bb[4]);
            float zz1 = sigmoidf_(acc[i][5] + bb[5]);
            float nn1 = tanhf(acc[i][6] + bb[6] + rr1 * (acc[i][7] + bb[7]));
            hnext[(long)r * 128 + ch0] = (1.0f - zz0) * nn0 + zz0 * hp0;
            hnext[(long)r * 128 + ch1] = (1.0f - zz1) * nn1 + zz1 * hp1;
        }
    }
}

// ----------------------- LayerNorm + GELU (in-place) -----------------------
__global__ __launch_bounds__(256) void ln_gelu_k(
    float* __restrict__ h0, const float* __restrict__ w, const float* __restrict__ b, int N)
{
    long t = (long)blockIdx.x * 256 + threadIdx.x;
    int n = (int)(t >> 5), lane = (int)(t & 31);
    if (n >= N) return;
    float* p = h0 + (long)n * 128 + lane * 4;
    float4 x = *(float4*)p;
    float s = x.x + x.y + x.z + x.w;
#pragma unroll
    for (int off = 16; off >= 1; off >>= 1) s += __shfl_xor(s, off);
    float mu = s * (1.0f / 128.0f);
    float4 d = make_float4(x.x - mu, x.y - mu, x.z - mu, x.w - mu);
    float ss = d.x * d.x + d.y * d.y + d.z * d.z + d.w * d.w;
#pragma unroll
    for (int off = 16; off >= 1; off >>= 1) ss += __shfl_xor(ss, off);
    float inv = 1.0f / sqrtf(ss * (1.0f / 128.0f) + 1e-5f);
    float4 wv = *(const float4*)(w + lane * 4);
    float4 bv = *(const float4*)(b + lane * 4);
    float y[4] = {d.x * inv * wv.x + bv.x, d.y * inv * wv.y + bv.y,
                  d.z * inv * wv.z + bv.z, d.w * inv * wv.w + bv.w};
#pragma unroll
    for (int i = 0; i < 4; i++)
        y[i] = 0.5f * y[i] * (1.0f + erff(y[i] * 0.70710678118654752f));
    *(float4*)p = make_float4(y[0], y[1], y[2], y[3]);
}

// --------------------------- broadcast h0 -> h[4] --------------------------
__global__ __launch_bounds__(256) void bcast4_k(
    const float4* __restrict__ src, float4* __restrict__ dst, long n4)
{
    long t = (long)blockIdx.x * 256 + threadIdx.x;
    if (t < n4) {
        float4 v = src[t];
        dst[t] = v; dst[n4 + t] = v; dst[2 * n4 + t] = v; dst[3 * n4 + t] = v;
    }
}

// ------------------------------ CSR build ----------------------------------
__global__ __launch_bounds__(256) void count_k(
    const int* __restrict__ dst, const int* __restrict__ et,
    int* __restrict__ cnt, int E, int N)
{
    int e = blockIdx.x * 256 + threadIdx.x;
    if (e >= E) return;
    int v = view_of(et[e]);
    atomicAdd(&cnt[v * N + dst[e]], 1);
}

__global__ __launch_bounds__(256) void scan1_k(
    const int* __restrict__ cnt, int* __restrict__ off, int* __restrict__ bsum, int n)
{
    __shared__ int sm[256];
    int base = blockIdx.x * 1024;
    int tid = threadIdx.x;
    int v[4]; int s = 0;
#pragma unroll
    for (int i = 0; i < 4; i++) {
        int idx = base + tid * 4 + i;
        v[i] = (idx < n) ? cnt[idx] : 0; s += v[i];
    }
    sm[tid] = s; __syncthreads();
    for (int o = 1; o < 256; o <<= 1) {
        int t2 = (tid >= o) ? sm[tid - o] : 0;
        __syncthreads(); sm[tid] += t2; __syncthreads();
    }
    int run = sm[tid] - s;
    if (tid == 255) bsum[blockIdx.x] = sm[255];
#pragma unroll
    for (int i = 0; i < 4; i++) {
        int idx = base + tid * 4 + i;
        if (idx < n) off[idx] = run;
        run += v[i];
    }
}

__global__ __launch_bounds__(256) void scan2_k(int* __restrict__ bsum, int nb)
{
    __shared__ int sm[256];
    int tid = threadIdx.x;
    int v = (tid < nb) ? bsum[tid] : 0;
    sm[tid] = v; __syncthreads();
    for (int o = 1; o < 256; o <<= 1) {
        int t2 = (tid >= o) ? sm[tid - o] : 0;
        __syncthreads(); sm[tid] += t2; __syncthreads();
    }
    if (tid < nb) bsum[tid] = sm[tid] - v;
}

__global__ __launch_bounds__(256) void scan3_k(
    int* __restrict__ off, int* __restrict__ cursor,
    const int* __restrict__ bsum, int n, int total)
{
    int i = blockIdx.x * 256 + threadIdx.x;
    if (i < n) {
        int o = off[i] + bsum[i >> 10];
        off[i] = o; cursor[i] = o;
    }
    if (i == 0) off[n] = total;
}

__global__ __launch_bounds__(256) void fill_k(
    const int* __restrict__ src, const int* __restrict__ dst,
    const int* __restrict__ et, int* __restrict__ cursor,
    int* __restrict__ esrc, int E, int N)
{
    int e = blockIdx.x * 256 + threadIdx.x;
    if (e >= E) return;
    int v = view_of(et[e]);
    int b = v * N + dst[e];
    int pos = atomicAdd(&cursor[b], 1);
    esrc[pos] = v * N + src[e];
}

// -------------------- CSR gather: agg[r] = sum m[esrc[j]] ------------------
__global__ __launch_bounds__(256) void gather_k(
    const float* __restrict__ m, float* __restrict__ agg,
    const int* __restrict__ off, const int* __restrict__ esrc, int R)
{
    long t = (long)blockIdx.x * 256 + threadIdx.x;
    int r = (int)(t >> 5), lane = (int)(t & 31);
    if (r >= R) return;
    int beg = off[r], end = off[r + 1];
    float4 acc = make_float4(0.f, 0.f, 0.f, 0.f);
    for (int j = beg; j < end; j++) {
        int s = esrc[j];
        float4 mv = *(const float4*)(m + (long)s * 128 + lane * 4);
        acc.x += mv.x; acc.y += mv.y; acc.z += mv.z; acc.w += mv.w;
    }
    *(float4*)(agg + (long)r * 128 + lane * 4) = acc;
}

// -------------------- per-view LayerNorm + residual (in-place) -------------
__global__ __launch_bounds__(256) void vln_res_k(
    float* __restrict__ h, const float* __restrict__ h0,
    const float* __restrict__ w, const float* __restrict__ b, int N)
{
    int v = blockIdx.z;
    long t = (long)blockIdx.x * 256 + threadIdx.x;
    int n = (int)(t >> 5), lane = (int)(t & 31);
    if (n >= N) return;
    float* hp = h + ((long)v * N + n) * 128 + lane * 4;
    float4 x = *(float4*)hp;
    float s = x.x + x.y + x.z + x.w;
#pragma unroll
    for (int off = 16; off >= 1; off >>= 1) s += __shfl_xor(s, off);
    float mu = s * (1.0f / 128.0f);
    float4 d = make_float4(x.x - mu, x.y - mu, x.z - mu, x.w - mu);
    float ss = d.x * d.x + d.y * d.y + d.z * d.z + d.w * d.w;
#pragma unroll
    for (int off = 16; off >= 1; off >>= 1) ss += __shfl_xor(ss, off);
    float inv = 1.0f / sqrtf(ss * (1.0f / 128.0f) + 1e-5f);
    float4 wv = *(const float4*)(w + v * 128 + lane * 4);
    float4 bv = *(const float4*)(b + v * 128 + lane * 4);
    float4 hv = *(const float4*)(h0 + (long)n * 128 + lane * 4);
    float4 r;
    r.x = d.x * inv * wv.x + bv.x + hv.x;
    r.y = d.y * inv * wv.y + bv.y + hv.y;
    r.z = d.z * inv * wv.z + bv.z + hv.z;
    r.w = d.w * inv * wv.w + bv.w + hv.w;
    *(float4*)hp = r;
}

// -------------- attention fusion (no atomics): fused[N,128] ----------------
__global__ __launch_bounds__(256) void fusion_k(
    const float* __restrict__ hs, const float* __restrict__ q,
    const float* __restrict__ u, const float* __restrict__ kb,
    float* __restrict__ fused, int N)
{
    long t = (long)blockIdx.x * 256 + threadIdx.x;
    int n = (int)(t >> 5), lane = (int)(t & 31);
    if (n >= N) return;
    long NH = (long)N * 128;
    float4 qv = *(const float4*)(q + (long)n * 128 + lane * 4);
    float4 kv = *(const float4*)(kb + lane * 4);
    float4 uv = *(const float4*)(u + (long)n * 128 + lane * 4);
    float part = qv.x * kv.x + qv.y * kv.y + qv.z * kv.z + qv.w * kv.w;
    float4 hv[4];
    float lg[4];
#pragma unroll
    for (int v = 0; v < 4; v++) {
        hv[v] = *(const float4*)(hs + v * NH + (long)n * 128 + lane * 4);
        lg[v] = hv[v].x * uv.x + hv[v].y * uv.y + hv[v].z * uv.z + hv[v].w * uv.w;
    }
#pragma unroll
    for (int off = 16; off >= 1; off >>= 1) {
        part += __shfl_xor(part, off);
#pragma unroll
        for (int v = 0; v < 4; v++) lg[v] += __shfl_xor(lg[v], off);
    }
    const float scale = 0.08838834764831845f;  // 128^-0.5
    float mx = -1e30f;
#pragma unroll
    for (int v = 0; v < 4; v++) { lg[v] = (lg[v] + part) * scale; mx = fmaxf(mx, lg[v]); }
    float se = 0.0f;
#pragma unroll
    for (int v = 0; v < 4; v++) { lg[v] = expf(lg[v] - mx); se += lg[v]; }
    float inv = 1.0f / se;
    float4 f = make_float4(0.f, 0.f, 0.f, 0.f);
#pragma unroll
    for (int v = 0; v < 4; v++) {
        float a = lg[v] * inv;
        f.x += a * hv[v].x; f.y += a * hv[v].y; f.z += a * hv[v].z; f.w += a * hv[v].w;
    }
    *(float4*)(fused + (long)n * 128 + lane * 4) = f;
}

// ------------- pooling: one block per graph (batch is sorted) --------------
__global__ __launch_bounds__(256) void pool_k(
    const float* __restrict__ fused, const int* __restrict__ batch,
    float* __restrict__ meanb, float* __restrict__ maxb, int N)
{
    __shared__ float s_sum[256], s_max[256];
    int b = blockIdx.x;
    // lower_bound(batch, b) / lower_bound(batch, b+1)
    int lo = 0, hi = N;
    while (lo < hi) { int mid = (lo + hi) >> 1; if (batch[mid] < b) lo = mid + 1; else hi = mid; }
    int beg = lo;
    lo = beg; hi = N;
    while (lo < hi) { int mid = (lo + hi) >> 1; if (batch[mid] < b + 1) lo = mid + 1; else hi = mid; }
    int end = lo;
    int tid = threadIdx.x;
    int c = tid & 127, half = tid >> 7;
    float sum = 0.0f, mx = __int_as_float(0xff800000);
    for (int n = beg + half; n < end; n += 2) {
        float v = fused[(long)n * 128 + c];
        sum += v; mx = fmaxf(mx, v);
    }
    s_sum[tid] = sum; s_max[tid] = mx;
    __syncthreads();
    if (half == 0) {
        float tot = s_sum[tid] + s_sum[tid + 128];
        float m2 = fmaxf(s_max[tid], s_max[tid + 128]);
        int cnt = end - beg;
        meanb[b * 128 + c] = tot / (float)max(cnt, 1);
        maxb[b * 128 + c] = m2;
    }
}

// ------------------------------ classifier MLP -----------------------------
__global__ __launch_bounds__(256) void classifier_k(
    const float* __restrict__ meanb, const float* __restrict__ maxb,
    const float* __restrict__ c1w, const float* __restrict__ c1b,
    const float* __restrict__ c2w, const float* __restrict__ c2b,
    const float* __restrict__ c3w, const float* __restrict__ c3b,
    float* __restrict__ out)
{
    __shared__ float sm[16384];
    int tid = threadIdx.x;
    for (int i = tid; i < 64 * 256; i += 256) {
        int b = i >> 8, k = i & 255;
        sm[i] = (k < 128) ? meanb[b * 128 + k] : maxb[b * 128 + (k - 128)];
    }
    __syncthreads();
    float r1[32];
    {
        int b = tid >> 2;
        int m0 = (tid & 3) * 32;
#pragma unroll
        for (int j = 0; j < 32; j++) r1[j] = c1b[m0 + j];
        for (int k = 0; k < 256; k++) {
            float gv = sm[b * 256 + k];
            const float* wr = c1w + k * 128 + m0;
#pragma unroll
            for (int j = 0; j < 32; j++) r1[j] += gv * wr[j];
        }
#pragma unroll
        for (int j = 0; j < 32; j++) r1[j] = fmaxf(r1[j], 0.0f);
    }
    __syncthreads();
    {
        int b = tid >> 2; int m0 = (tid & 3) * 32;
#pragma unroll
        for (int j = 0; j < 32; j++) sm[b * 128 + m0 + j] = r1[j];
    }
    __syncthreads();
    float r2[16];
    {
        int b = tid >> 2; int m0 = (tid & 3) * 16;
#pragma unroll
        for (int j = 0; j < 16; j++) r2[j] = c2b[m0 + j];
        for (int k = 0; k < 128; k++) {
            float hvv = sm[b * 128 + k];
            const float* wr = c2w + k * 64 + m0;
#pragma unroll
            for (int j = 0; j < 16; j++) r2[j] += hvv * wr[j];
        }
#pragma unroll
        for (int j = 0; j < 16; j++) r2[j] = fmaxf(r2[j], 0.0f);
    }
    __syncthreads();
    {
        int b = tid >> 2; int m0 = (tid & 3) * 16;
#pragma unroll
        for (int j = 0; j < 16; j++) sm[8192 + b * 64 + m0 + j] = r2[j];
    }
    __syncthreads();
    if (tid < 64) {
        float acc = c3b[0];
        for (int j = 0; j < 64; j++) acc += sm[8192 + tid * 64 + j] * c3w[j];
        out[tid] = acc;
    }
}

// ---------------------------------------------------------------------------
extern "C" void kernel_launch(void* const* d_in, const int* in_sizes, int n_in,
                              void* d_out, int out_size, void* d_ws, size_t ws_size,
                              hipStream_t stream) {
    (void)n_in; (void)out_size; (void)ws_size;
    const float* x      = (const float*)d_in[0];
    const int*   eidx   = (const int*)d_in[1];
    const int*   etype  = (const int*)d_in[2];
    const int*   batch  = (const int*)d_in[3];
    const float* proj_w = (const float*)d_in[4];
    const float* proj_b = (const float*)d_in[5];
    const float* ln0_w  = (const float*)d_in[6];
    const float* ln0_b  = (const float*)d_in[7];
    const float* ggnn_w = (const float*)d_in[8];
    const float* gwih   = (const float*)d_in[9];
    const float* gwhh   = (const float*)d_in[10];
    const float* gbih   = (const float*)d_in[11];
    const float* gbhh   = (const float*)d_in[12];
    const float* vln_w  = (const float*)d_in[13];
    const float* vln_b  = (const float*)d_in[14];
    const float* q_w    = (const float*)d_in[15];
    const float* q_b    = (const float*)d_in[16];
    const float* k_w    = (const float*)d_in[17];
    const float* k_b    = (const float*)d_in[18];
    const float* c1w    = (const float*)d_in[19];
    const float* c1b    = (const float*)d_in[20];
    const float* c2w    = (const float*)d_in[21];
    const float* c2b    = (const float*)d_in[22];
    const float* c3w    = (const float*)d_in[23];
    const float* c3b    = (const float*)d_in[24];
    float* out = (float*)d_out;

    const int N = in_sizes[3];
    const int E = in_sizes[2];
    const int IN = in_sizes[0] / N;
    const int H = 128, L = 4;
    const int N4 = 4 * N;

    long NH = (long)N * H;
    float* ws = (float*)d_ws;
    float* h0 = ws;             // NH
    float* bufX = h0 + NH;      // 4*NH
    float* bufY = bufX + 4 * NH; // 4*NH (agg)
    float* bufZ = bufY + 4 * NH; // 4*NH
    float* poolMean = bufZ + 4 * NH;     // 64*128
    float* poolMax  = poolMean + 64 * H; // 64*128
    float* wp = poolMax + 64 * H;        // 4*256*512
    float* bp = wp + 4 * 256 * 512;      // 4*512
    int* iOff  = (int*)(bp + 4 * 512);   // N4+1
    int* iCnt  = iOff + N4 + 1;
    int* iCur  = iCnt + N4;
    int* iBsum = iCur + N4;              // 256
    int* iEsrc = iBsum + 256;            // E

    int gx = (N + 127) / 128;
    int rb = (int)(((long)N * 32 + 255) / 256);
    int eb = (E + 255) / 256;
    int nbScan = (N4 + 1023) / 1024;

    const int* esrc_in = eidx;
    const int* edst_in = eidx + E;

    // ---- CSR build + repacked GRU weights (once per call) ----
    hipMemsetAsync(iCnt, 0, (size_t)N4 * sizeof(int), stream);
    count_k<<<eb, 256, 0, stream>>>(edst_in, etype, iCnt, E, N);
    scan1_k<<<nbScan, 256, 0, stream>>>(iCnt, iOff, iBsum, N4);
    scan2_k<<<1, 256, 0, stream>>>(iBsum, nbScan);
    scan3_k<<<(N4 + 255) / 256, 256, 0, stream>>>(iOff, iCur, iBsum, N4, E);
    fill_k<<<eb, 256, 0, stream>>>(esrc_in, edst_in, etype, iCur, iEsrc, E, N);
    build_wp_k<<<(4 * 256 * 512 + 255) / 256, 256, 0, stream>>>(
        gwih, gwhh, gbih, gbhh, wp, bp);

    // 1. input projection + LN + GELU
    gemm_k<false, 0><<<dim3(gx, 1, 1), 256, 0, stream>>>(
        x, proj_w, proj_b, h0, N, H, IN, 0, 0, 0);
    ln_gelu_k<<<rb, 256, 0, stream>>>(h0, ln0_w, ln0_b, N);
    bcast4_k<<<(int)((NH / 4 + 255) / 256), 256, 0, stream>>>(
        (const float4*)h0, (float4*)bufX, NH / 4);

    float* hcur = bufX;
    for (int i = 0; i < L; i++) {
        float* mbuf = (hcur == bufX) ? bufZ : bufX;
        // m[v] = h[v] @ ggnn_w[v][i]
        gemm_k<false, 0><<<dim3(gx, 1, 4), 256, 0, stream>>>(
            hcur, ggnn_w + (long)i * H * H, nullptr, mbuf,
            N, H, H, NH, (long)L * H * H, NH);
        gather_k<<<(int)(((long)N4 * 32 + 255) / 256), 256, 0, stream>>>(
            mbuf, bufY, iOff, iEsrc, N4);
        // fused GRU GEMM: (agg=bufY, hcur) -> mbuf (m is dead)
        gemm_gru_k<<<dim3(gx, 4, 4), 256, 0, stream>>>(
            bufY, hcur, wp, bp, mbuf, N, NH);
        hcur = mbuf;
    }

    // per-view LN + residual (hcur becomes hs)
    vln_res_k<<<dim3(rb, 1, 4), 256, 0, stream>>>(hcur, h0, vln_w, vln_b, N);

    // attention: q = tanh(h0@q_w + q_b); u = q @ k_w^T; fused nodes
    float* q = bufY;
    float* u = bufY + NH;
    float* fused = bufY + 2 * NH;
    gemm_k<false, 1><<<dim3(gx, 1, 1), 256, 0, stream>>>(
        h0, q_w, q_b, q, N, H, H, 0, 0, 0);
    gemm_k<true, 0><<<dim3(gx, 1, 1), 256, 0, stream>>>(
        q, k_w, nullptr, u, N, H, H, 0, 0, 0);
    fusion_k<<<rb, 256, 0, stream>>>(hcur, q, u, k_b, fused, N);
    pool_k<<<64, 256, 0, stream>>>(fused, batch, poolMean, poolMax, N);
    classifier_k<<<1, 256, 0, stream>>>(
        poolMean, poolMax, c1w, c1b, c2w, c2b, c3w, c3b, out);
}

// Round 4
// 2080.527 us; speedup vs baseline: 4.0857x; 2.1862x over previous
//
#include <hip/hip_runtime.h>
#include <math.h>

// ---------------------------------------------------------------------------
// MultiViewEPSSClassifier forward. N=50000, E=600000, IN=512, H=128, B=64, L=4.
// R2: atomic scatter -> CSR gather.
// R3: atomic-free pooling; GRU fused into one GEMM (gate-interleaved W').
// R4: (a) fold ggnn_w into GRU A-side weights: gather(h@Wg)=gather(h)@Wg, so
//         gi = S @ (Wg@Wih^T) -- m-GEMMs and m-buffer deleted;
//     (b) fused GRU GEMM -> MFMA bf16: A split hi/lo (2-pass, ~2^-17), B
//         single bf16 RTN (weights ~0.02 scale). 16x16x32 tiles, 64x256
//         block, quad-shuffle GRU epilogue.
// ---------------------------------------------------------------------------

typedef __attribute__((ext_vector_type(8))) short short8;
typedef __attribute__((ext_vector_type(4))) float floatx4;

__device__ __forceinline__ unsigned short f2bf_rtn(float x) {
    unsigned u = __float_as_uint(x);
    return (unsigned short)((u + 0x7FFFu + ((u >> 16) & 1u)) >> 16);
}

// types {0,9,10}->0, {1,2,3}->1, {4,5,6}->2, {7,8,11,12}->3 (partition of 0..12)
__device__ __forceinline__ int view_of(int t) {
    return (t >= 1 && t <= 3) ? 1 : (t >= 4 && t <= 6) ? 2
         : ((t == 7) || (t == 8) || (t >= 11)) ? 3 : 0;
}

// ------------------------- fp32 GEMM (proj / attn / Wcomb) -----------------
template <bool BT, int EPI>
__global__ __launch_bounds__(256, 2) void gemm_k(
    const float* __restrict__ A, const float* __restrict__ Bm,
    const float* __restrict__ bias, float* __restrict__ C,
    int N, int M, int K, long sA, long sB, long sC)
{
    __shared__ float As[32][132];
    __shared__ float Bs[32][132];
    A  += (long)blockIdx.z * sA;
    Bm += (long)blockIdx.z * sB;
    C  += (long)blockIdx.z * sC;
    const int r0 = blockIdx.x * 128;
    const int c0 = blockIdx.y * 128;
    const int tid = threadIdx.x;
    const int tx = tid & 15;
    const int ty = tid >> 4;

    float acc[8][8];
#pragma unroll
    for (int i = 0; i < 8; i++)
#pragma unroll
        for (int j = 0; j < 8; j++) acc[i][j] = 0.0f;

    for (int k0 = 0; k0 < K; k0 += 32) {
        {
            int arow = tid >> 3;
            int akq  = (tid & 7) << 2;
#pragma unroll
            for (int hh = 0; hh < 4; hh++) {
                int r  = arow + hh * 32;
                int gr = r0 + r;
                float4 av = make_float4(0.f, 0.f, 0.f, 0.f);
                if (gr < N) av = *(const float4*)(A + (long)gr * K + k0 + akq);
                As[akq + 0][r] = av.x; As[akq + 1][r] = av.y;
                As[akq + 2][r] = av.z; As[akq + 3][r] = av.w;
            }
        }
        if (BT) {
            int brow = tid >> 3;
            int bkq  = (tid & 7) << 2;
#pragma unroll
            for (int hh = 0; hh < 4; hh++) {
                int r = brow + hh * 32;
                float4 bv = *(const float4*)(Bm + (long)(c0 + r) * K + k0 + bkq);
                Bs[bkq + 0][r] = bv.x; Bs[bkq + 1][r] = bv.y;
                Bs[bkq + 2][r] = bv.z; Bs[bkq + 3][r] = bv.w;
            }
        } else {
            int kk0 = tid >> 5;
            int bmq = (tid & 31) << 2;
#pragma unroll
            for (int hh = 0; hh < 4; hh++) {
                int kk = kk0 + hh * 8;
                float4 bv = *(const float4*)(Bm + (long)(k0 + kk) * M + c0 + bmq);
                *(float4*)&Bs[kk][bmq] = bv;
            }
        }
        __syncthreads();
#pragma unroll
        for (int k = 0; k < 32; k++) {
            float4 a0 = *(const float4*)&As[k][ty << 2];
            float4 a1 = *(const float4*)&As[k][64 + (ty << 2)];
            float4 b0 = *(const float4*)&Bs[k][tx << 2];
            float4 b1 = *(const float4*)&Bs[k][64 + (tx << 2)];
            float av[8] = {a0.x, a0.y, a0.z, a0.w, a1.x, a1.y, a1.z, a1.w};
            float bv[8] = {b0.x, b0.y, b0.z, b0.w, b1.x, b1.y, b1.z, b1.w};
#pragma unroll
            for (int i = 0; i < 8; i++)
#pragma unroll
                for (int j = 0; j < 8; j++) acc[i][j] += av[i] * bv[j];
        }
        __syncthreads();
    }

    float bb[8] = {0, 0, 0, 0, 0, 0, 0, 0};
    if (bias) {
        float4 b0 = *(const float4*)(bias + c0 + (tx << 2));
        float4 b1 = *(const float4*)(bias + c0 + 64 + (tx << 2));
        bb[0] = b0.x; bb[1] = b0.y; bb[2] = b0.z; bb[3] = b0.w;
        bb[4] = b1.x; bb[5] = b1.y; bb[6] = b1.z; bb[7] = b1.w;
    }
#pragma unroll
    for (int i = 0; i < 8; i++) {
        int r = (i < 4) ? (r0 + (ty << 2) + i) : (r0 + 64 + (ty << 2) + i - 4);
        if (r < N) {
            float v[8];
#pragma unroll
            for (int j = 0; j < 8; j++) {
                v[j] = acc[i][j] + bb[j];
                if (EPI == 1) v[j] = tanhf(v[j]);
            }
            *(float4*)(C + (long)r * M + c0 + (tx << 2)) = make_float4(v[0], v[1], v[2], v[3]);
            *(float4*)(C + (long)r * M + c0 + 64 + (tx << 2)) = make_float4(v[4], v[5], v[6], v[7]);
        }
    }
}

// ---------- build P_ih_rep[16][128][512], P_hh[4][128][512], bias ----------
// col m = ch*4+g; gates 0=r,1=z,2=inn(agg-side only),3=hn(h-side only).
__global__ __launch_bounds__(256) void build_p_k(
    const float* __restrict__ gwih, const float* __restrict__ gwhh,
    const float* __restrict__ gbih, const float* __restrict__ gbhh,
    float* __restrict__ pih, float* __restrict__ phh, float* __restrict__ bp)
{
    int idx = blockIdx.x * 256 + threadIdx.x;
    if (idx < 16 * 65536) {
        int z = idx >> 16, rem = idx & 65535;
        int k = rem >> 9, mcol = rem & 511;
        int ch = mcol >> 2, g = mcol & 3;
        int v = z >> 2;
        const float* Wih = gwih + (long)v * 384 * 128;
        float val = 0.0f;
        if (g == 0) val = Wih[ch * 128 + k];
        else if (g == 1) val = Wih[(128 + ch) * 128 + k];
        else if (g == 2) val = Wih[(256 + ch) * 128 + k];
        pih[idx] = val;
    }
    if (idx < 4 * 65536) {
        int v = idx >> 16, rem = idx & 65535;
        int k = rem >> 9, mcol = rem & 511;
        int ch = mcol >> 2, g = mcol & 3;
        const float* Whh = gwhh + (long)v * 384 * 128;
        float val = 0.0f;
        if (g == 0) val = Whh[ch * 128 + k];
        else if (g == 1) val = Whh[(128 + ch) * 128 + k];
        else if (g == 3) val = Whh[(256 + ch) * 128 + k];
        phh[idx] = val;
    }
    if (idx < 4 * 512) {
        int v = idx >> 9, mcol = idx & 511;
        int ch = mcol >> 2, g = mcol & 3;
        float val;
        if (g == 0) val = gbih[v * 384 + ch] + gbhh[v * 384 + ch];
        else if (g == 1) val = gbih[v * 384 + 128 + ch] + gbhh[v * 384 + 128 + ch];
        else if (g == 2) val = gbih[v * 384 + 256 + ch];
        else val = gbhh[v * 384 + 256 + ch];
        bp[idx] = val;
    }
}

// ---- pack combined weights -> bf16 frag order Bp[z][ks][col][qq][j] -------
// row k<128: Wcomb[z] (= Wg@P_ih), k>=128: P_hh[z>>2].
__global__ __launch_bounds__(256) void pack_b_k(
    const float* __restrict__ wcomb, const float* __restrict__ phh,
    short* __restrict__ Bp)
{
    int idx = blockIdx.x * 256 + threadIdx.x;
    if (idx >= 16 * 256 * 512) return;
    int z = idx >> 17, rem = idx & 131071;
    int k = rem >> 9, col = rem & 511;
    float val = (k < 128) ? wcomb[(long)z * 65536 + k * 512 + col]
                          : phh[(long)(z >> 2) * 65536 + (k - 128) * 512 + col];
    long dst = ((long)(z * 8 + (k >> 5)) * 512 + col) * 32 + ((k >> 3) & 3) * 8 + (k & 7);
    Bp[dst] = (short)f2bf_rtn(val);
}

// -------------- MFMA fused GRU GEMM: h_next = GRU(S, h_cur) ----------------
// C-space [N x 512] per view (cols = ch*4+gate), K=256 over [S|h].
// Block: 64 rows x 256 cols, 4 waves of 32r x 128c, 16x16x32 bf16 tiles.
// A: fp32 -> bf16 hi/lo in-kernel (2 MFMA passes). B: pre-packed bf16.
__global__ __launch_bounds__(256, 3) void gemm_gru_mfma_k(
    const float* __restrict__ S, const float* __restrict__ hcur,
    const short* __restrict__ Bp, const float* __restrict__ bp,
    float* __restrict__ hnext, int N, long sA)
{
    __shared__ __align__(16) short Ahi[64 * 40];   // stride 40 bf16 (80B) pad
    __shared__ __align__(16) short Alo[64 * 40];
    __shared__ __align__(16) short Bsm[256 * 40];
    const int z = blockIdx.z;
    S     += (long)z * sA;
    hcur  += (long)z * sA;
    Bp    += (long)z * 524288;      // 4 layers x 131072 per (v,i); layer in host ptr
    bp    += (long)z * 512;
    hnext += (long)z * sA;
    const int r0  = blockIdx.x * 64;
    const int c0b = blockIdx.y * 256;
    const int tid = threadIdx.x;
    const int l = tid & 63, w = tid >> 6;
    const int wrow = (w & 1) * 32, wcol = (w >> 1) * 128;
    const int m = l & 15, q = l >> 4;

    floatx4 acc[2][8];
#pragma unroll
    for (int a = 0; a < 2; a++)
#pragma unroll
        for (int b = 0; b < 8; b++) acc[a][b] = (floatx4)0.0f;

    const int arow = tid >> 2;
    const int fcol = (tid & 3) * 8;
    const int gr = r0 + arow;

    for (int ks = 0; ks < 8; ks++) {
        // ---- stage A tile 64x32: fp32 -> bf16 hi/lo ----
        const float* Asrc = (ks < 4) ? S : hcur;
        const int kc = (ks & 3) * 32 + fcol;
        float xv[8];
        if (gr < N) {
            float4 x0 = *(const float4*)(Asrc + (long)gr * 128 + kc);
            float4 x1 = *(const float4*)(Asrc + (long)gr * 128 + kc + 4);
            xv[0] = x0.x; xv[1] = x0.y; xv[2] = x0.z; xv[3] = x0.w;
            xv[4] = x1.x; xv[5] = x1.y; xv[6] = x1.z; xv[7] = x1.w;
        } else {
#pragma unroll
            for (int u = 0; u < 8; u++) xv[u] = 0.0f;
        }
        short8 vhi, vlo;
#pragma unroll
        for (int u = 0; u < 8; u++) {
            unsigned short hb = f2bf_rtn(xv[u]);
            float fh = __uint_as_float((unsigned)hb << 16);
            vhi[u] = (short)hb;
            vlo[u] = (short)f2bf_rtn(xv[u] - fh);
        }
        *(short8*)&Ahi[arow * 40 + fcol] = vhi;
        *(short8*)&Alo[arow * 40 + fcol] = vlo;
        // ---- stage B tile 32k x 256 cols (bf16 copy, re-pad) ----
        {
            const short* bsrc = Bp + (long)ks * 16384 + (long)c0b * 32 + tid * 32;
#pragma unroll
            for (int u = 0; u < 4; u++) {
                short8 bv = *(const short8*)(bsrc + u * 8);
                *(short8*)&Bsm[tid * 40 + u * 8] = bv;
            }
        }
        __syncthreads();
        short8 a_hi0 = *(short8*)&Ahi[(wrow + m) * 40 + q * 8];
        short8 a_lo0 = *(short8*)&Alo[(wrow + m) * 40 + q * 8];
        short8 a_hi1 = *(short8*)&Ahi[(wrow + 16 + m) * 40 + q * 8];
        short8 a_lo1 = *(short8*)&Alo[(wrow + 16 + m) * 40 + q * 8];
#pragma unroll
        for (int tn = 0; tn < 8; tn++) {
            short8 bf = *(short8*)&Bsm[(wcol + tn * 16 + m) * 40 + q * 8];
            acc[0][tn] = __builtin_amdgcn_mfma_f32_16x16x32_bf16(a_hi0, bf, acc[0][tn], 0, 0, 0);
            acc[0][tn] = __builtin_amdgcn_mfma_f32_16x16x32_bf16(a_lo0, bf, acc[0][tn], 0, 0, 0);
            acc[1][tn] = __builtin_amdgcn_mfma_f32_16x16x32_bf16(a_hi1, bf, acc[1][tn], 0, 0, 0);
            acc[1][tn] = __builtin_amdgcn_mfma_f32_16x16x32_bf16(a_lo1, bf, acc[1][tn], 0, 0, 0);
        }
        __syncthreads();
    }

    // ---- GRU epilogue: quad (4 gate cols) -> per-lane row via shuffles ----
    const int g = l & 3;
    const int q0 = l & ~3;
#pragma unroll
    for (int tm = 0; tm < 2; tm++) {
        const int row = r0 + wrow + tm * 16 + q * 4 + g;  // this lane's reg i=g
#pragma unroll
        for (int tn = 0; tn < 8; tn++) {
            floatx4 a = acc[tm][tn];
            float vr = 0.f, vz = 0.f, vn = 0.f, vh = 0.f;
#pragma unroll
            for (int i = 0; i < 4; i++) {
                float t0 = __shfl(a[i], q0 + 0);
                float t1 = __shfl(a[i], q0 + 1);
                float t2 = __shfl(a[i], q0 + 2);
                float t3 = __shfl(a[i], q0 + 3);
                if (g == i) { vr = t0; vz = t1; vn = t2; vh = t3; }
            }
            const int colq = c0b + wcol + tn * 16 + (m & ~3);
            if (row < N) {
                float4 bv = *(const float4*)(bp + colq);
                int ch = colq >> 2;
                float hp = hcur[(long)row * 128 + ch];
                float rr = 1.0f / (1.0f + expf(-(vr + bv.x)));
                float zz = 1.0f / (1.0f + expf(-(vz + bv.y)));
                float nn = tanhf(vn + bv.z + rr * (vh + bv.w));
                hnext[(long)row * 128 + ch] = (1.0f - zz) * nn + zz * hp;
            }
        }
    }
}

// ----------------------- LayerNorm + GELU (in-place) -----------------------
__global__ __launch_bounds__(256) void ln_gelu_k(
    float* __restrict__ h0, const float* __restrict__ w, const float* __restrict__ b, int N)
{
    long t = (long)blockIdx.x * 256 + threadIdx.x;
    int n = (int)(t >> 5), lane = (int)(t & 31);
    if (n >= N) return;
    float* p = h0 + (long)n * 128 + lane * 4;
    float4 x = *(float4*)p;
    float s = x.x + x.y + x.z + x.w;
#pragma unroll
    for (int off = 16; off >= 1; off >>= 1) s += __shfl_xor(s, off);
    float mu = s * (1.0f / 128.0f);
    float4 d = make_float4(x.x - mu, x.y - mu, x.z - mu, x.w - mu);
    float ss = d.x * d.x + d.y * d.y + d.z * d.z + d.w * d.w;
#pragma unroll
    for (int off = 16; off >= 1; off >>= 1) ss += __shfl_xor(ss, off);
    float inv = 1.0f / sqrtf(ss * (1.0f / 128.0f) + 1e-5f);
    float4 wv = *(const float4*)(w + lane * 4);
    float4 bv = *(const float4*)(b + lane * 4);
    float y[4] = {d.x * inv * wv.x + bv.x, d.y * inv * wv.y + bv.y,
                  d.z * inv * wv.z + bv.z, d.w * inv * wv.w + bv.w};
#pragma unroll
    for (int i = 0; i < 4; i++)
        y[i] = 0.5f * y[i] * (1.0f + erff(y[i] * 0.70710678118654752f));
    *(float4*)p = make_float4(y[0], y[1], y[2], y[3]);
}

// --------------------------- broadcast h0 -> h[4] --------------------------
__global__ __launch_bounds__(256) void bcast4_k(
    const float4* __restrict__ src, float4* __restrict__ dst, long n4)
{
    long t = (long)blockIdx.x * 256 + threadIdx.x;
    if (t < n4) {
        float4 v = src[t];
        dst[t] = v; dst[n4 + t] = v; dst[2 * n4 + t] = v; dst[3 * n4 + t] = v;
    }
}

// ------------------------------ CSR build ----------------------------------
__global__ __launch_bounds__(256) void count_k(
    const int* __restrict__ dst, const int* __restrict__ et,
    int* __restrict__ cnt, int E, int N)
{
    int e = blockIdx.x * 256 + threadIdx.x;
    if (e >= E) return;
    int v = view_of(et[e]);
    atomicAdd(&cnt[v * N + dst[e]], 1);
}

__global__ __launch_bounds__(256) void scan1_k(
    const int* __restrict__ cnt, int* __restrict__ off, int* __restrict__ bsum, int n)
{
    __shared__ int sm[256];
    int base = blockIdx.x * 1024;
    int tid = threadIdx.x;
    int v[4]; int s = 0;
#pragma unroll
    for (int i = 0; i < 4; i++) {
        int idx = base + tid * 4 + i;
        v[i] = (idx < n) ? cnt[idx] : 0; s += v[i];
    }
    sm[tid] = s; __syncthreads();
    for (int o = 1; o < 256; o <<= 1) {
        int t2 = (tid >= o) ? sm[tid - o] : 0;
        __syncthreads(); sm[tid] += t2; __syncthreads();
    }
    int run = sm[tid] - s;
    if (tid == 255) bsum[blockIdx.x] = sm[255];
#pragma unroll
    for (int i = 0; i < 4; i++) {
        int idx = base + tid * 4 + i;
        if (idx < n) off[idx] = run;
        run += v[i];
    }
}

__global__ __launch_bounds__(256) void scan2_k(int* __restrict__ bsum, int nb)
{
    __shared__ int sm[256];
    int tid = threadIdx.x;
    int v = (tid < nb) ? bsum[tid] : 0;
    sm[tid] = v; __syncthreads();
    for (int o = 1; o < 256; o <<= 1) {
        int t2 = (tid >= o) ? sm[tid - o] : 0;
        __syncthreads(); sm[tid] += t2; __syncthreads();
    }
    if (tid < nb) bsum[tid] = sm[tid] - v;
}

__global__ __launch_bounds__(256) void scan3_k(
    int* __restrict__ off, int* __restrict__ cursor,
    const int* __restrict__ bsum, int n, int total)
{
    int i = blockIdx.x * 256 + threadIdx.x;
    if (i < n) {
        int o = off[i] + bsum[i >> 10];
        off[i] = o; cursor[i] = o;
    }
    if (i == 0) off[n] = total;
}

__global__ __launch_bounds__(256) void fill_k(
    const int* __restrict__ src, const int* __restrict__ dst,
    const int* __restrict__ et, int* __restrict__ cursor,
    int* __restrict__ esrc, int E, int N)
{
    int e = blockIdx.x * 256 + threadIdx.x;
    if (e >= E) return;
    int v = view_of(et[e]);
    int b = v * N + dst[e];
    int pos = atomicAdd(&cursor[b], 1);
    esrc[pos] = v * N + src[e];
}

// -------------------- CSR gather: S[r] = sum h[esrc[j]] --------------------
__global__ __launch_bounds__(256) void gather_k(
    const float* __restrict__ m, float* __restrict__ agg,
    const int* __restrict__ off, const int* __restrict__ esrc, int R)
{
    long t = (long)blockIdx.x * 256 + threadIdx.x;
    int r = (int)(t >> 5), lane = (int)(t & 31);
    if (r >= R) return;
    int beg = off[r], end = off[r + 1];
    float4 acc = make_float4(0.f, 0.f, 0.f, 0.f);
    for (int j = beg; j < end; j++) {
        int s = esrc[j];
        float4 mv = *(const float4*)(m + (long)s * 128 + lane * 4);
        acc.x += mv.x; acc.y += mv.y; acc.z += mv.z; acc.w += mv.w;
    }
    *(float4*)(agg + (long)r * 128 + lane * 4) = acc;
}

// -------------------- per-view LayerNorm + residual (in-place) -------------
__global__ __launch_bounds__(256) void vln_res_k(
    float* __restrict__ h, const float* __restrict__ h0,
    const float* __restrict__ w, const float* __restrict__ b, int N)
{
    int v = blockIdx.z;
    long t = (long)blockIdx.x * 256 + threadIdx.x;
    int n = (int)(t >> 5), lane = (int)(t & 31);
    if (n >= N) return;
    float* hp = h + ((long)v * N + n) * 128 + lane * 4;
    float4 x = *(float4*)hp;
    float s = x.x + x.y + x.z + x.w;
#pragma unroll
    for (int off = 16; off >= 1; off >>= 1) s += __shfl_xor(s, off);
    float mu = s * (1.0f / 128.0f);
    float4 d = make_float4(x.x - mu, x.y - mu, x.z - mu, x.w - mu);
    float ss = d.x * d.x + d.y * d.y + d.z * d.z + d.w * d.w;
#pragma unroll
    for (int off = 16; off >= 1; off >>= 1) ss += __shfl_xor(ss, off);
    float inv = 1.0f / sqrtf(ss * (1.0f / 128.0f) + 1e-5f);
    float4 wv = *(const float4*)(w + v * 128 + lane * 4);
    float4 bv = *(const float4*)(b + v * 128 + lane * 4);
    float4 hv = *(const float4*)(h0 + (long)n * 128 + lane * 4);
    float4 r;
    r.x = d.x * inv * wv.x + bv.x + hv.x;
    r.y = d.y * inv * wv.y + bv.y + hv.y;
    r.z = d.z * inv * wv.z + bv.z + hv.z;
    r.w = d.w * inv * wv.w + bv.w + hv.w;
    *(float4*)hp = r;
}

// -------------- attention fusion (no atomics): fused[N,128] ----------------
__global__ __launch_bounds__(256) void fusion_k(
    const float* __restrict__ hs, const float* __restrict__ q,
    const float* __restrict__ u, const float* __restrict__ kb,
    float* __restrict__ fused, int N)
{
    long t = (long)blockIdx.x * 256 + threadIdx.x;
    int n = (int)(t >> 5), lane = (int)(t & 31);
    if (n >= N) return;
    long NH = (long)N * 128;
    float4 qv = *(const float4*)(q + (long)n * 128 + lane * 4);
    float4 kv = *(const float4*)(kb + lane * 4);
    float4 uv = *(const float4*)(u + (long)n * 128 + lane * 4);
    float part = qv.x * kv.x + qv.y * kv.y + qv.z * kv.z + qv.w * kv.w;
    float4 hv[4];
    float lg[4];
#pragma unroll
    for (int v = 0; v < 4; v++) {
        hv[v] = *(const float4*)(hs + v * NH + (long)n * 128 + lane * 4);
        lg[v] = hv[v].x * uv.x + hv[v].y * uv.y + hv[v].z * uv.z + hv[v].w * uv.w;
    }
#pragma unroll
    for (int off = 16; off >= 1; off >>= 1) {
        part += __shfl_xor(part, off);
#pragma unroll
        for (int v = 0; v < 4; v++) lg[v] += __shfl_xor(lg[v], off);
    }
    const float scale = 0.08838834764831845f;
    float mx = -1e30f;
#pragma unroll
    for (int v = 0; v < 4; v++) { lg[v] = (lg[v] + part) * scale; mx = fmaxf(mx, lg[v]); }
    float se = 0.0f;
#pragma unroll
    for (int v = 0; v < 4; v++) { lg[v] = expf(lg[v] - mx); se += lg[v]; }
    float inv = 1.0f / se;
    float4 f = make_float4(0.f, 0.f, 0.f, 0.f);
#pragma unroll
    for (int v = 0; v < 4; v++) {
        float a = lg[v] * inv;
        f.x += a * hv[v].x; f.y += a * hv[v].y; f.z += a * hv[v].z; f.w += a * hv[v].w;
    }
    *(float4*)(fused + (long)n * 128 + lane * 4) = f;
}

// ------------- pooling: one block per graph (batch is sorted) --------------
__global__ __launch_bounds__(256) void pool_k(
    const float* __restrict__ fused, const int* __restrict__ batch,
    float* __restrict__ meanb, float* __restrict__ maxb, int N)
{
    __shared__ float s_sum[256], s_max[256];
    int b = blockIdx.x;
    int lo = 0, hi = N;
    while (lo < hi) { int mid = (lo + hi) >> 1; if (batch[mid] < b) lo = mid + 1; else hi = mid; }
    int beg = lo;
    lo = beg; hi = N;
    while (lo < hi) { int mid = (lo + hi) >> 1; if (batch[mid] < b + 1) lo = mid + 1; else hi = mid; }
    int end = lo;
    int tid = threadIdx.x;
    int c = tid & 127, half = tid >> 7;
    float sum = 0.0f, mx = __int_as_float(0xff800000);
    for (int n = beg + half; n < end; n += 2) {
        float v = fused[(long)n * 128 + c];
        sum += v; mx = fmaxf(mx, v);
    }
    s_sum[tid] = sum; s_max[tid] = mx;
    __syncthreads();
    if (half == 0) {
        float tot = s_sum[tid] + s_sum[tid + 128];
        float m2 = fmaxf(s_max[tid], s_max[tid + 128]);
        int cnt = end - beg;
        meanb[b * 128 + c] = tot / (float)max(cnt, 1);
        maxb[b * 128 + c] = m2;
    }
}

// ------------------------------ classifier MLP -----------------------------
__global__ __launch_bounds__(256) void classifier_k(
    const float* __restrict__ meanb, const float* __restrict__ maxb,
    const float* __restrict__ c1w, const float* __restrict__ c1b,
    const float* __restrict__ c2w, const float* __restrict__ c2b,
    const float* __restrict__ c3w, const float* __restrict__ c3b,
    float* __restrict__ out)
{
    __shared__ float sm[16384];
    int tid = threadIdx.x;
    for (int i = tid; i < 64 * 256; i += 256) {
        int b = i >> 8, k = i & 255;
        sm[i] = (k < 128) ? meanb[b * 128 + k] : maxb[b * 128 + (k - 128)];
    }
    __syncthreads();
    float r1[32];
    {
        int b = tid >> 2;
        int m0 = (tid & 3) * 32;
#pragma unroll
        for (int j = 0; j < 32; j++) r1[j] = c1b[m0 + j];
        for (int k = 0; k < 256; k++) {
            float gv = sm[b * 256 + k];
            const float* wr = c1w + k * 128 + m0;
#pragma unroll
            for (int j = 0; j < 32; j++) r1[j] += gv * wr[j];
        }
#pragma unroll
        for (int j = 0; j < 32; j++) r1[j] = fmaxf(r1[j], 0.0f);
    }
    __syncthreads();
    {
        int b = tid >> 2; int m0 = (tid & 3) * 32;
#pragma unroll
        for (int j = 0; j < 32; j++) sm[b * 128 + m0 + j] = r1[j];
    }
    __syncthreads();
    float r2[16];
    {
        int b = tid >> 2; int m0 = (tid & 3) * 16;
#pragma unroll
        for (int j = 0; j < 16; j++) r2[j] = c2b[m0 + j];
        for (int k = 0; k < 128; k++) {
            float hvv = sm[b * 128 + k];
            const float* wr = c2w + k * 64 + m0;
#pragma unroll
            for (int j = 0; j < 16; j++) r2[j] += hvv * wr[j];
        }
#pragma unroll
        for (int j = 0; j < 16; j++) r2[j] = fmaxf(r2[j], 0.0f);
    }
    __syncthreads();
    {
        int b = tid >> 2; int m0 = (tid & 3) * 16;
#pragma unroll
        for (int j = 0; j < 16; j++) sm[8192 + b * 64 + m0 + j] = r2[j];
    }
    __syncthreads();
    if (tid < 64) {
        float acc = c3b[0];
        for (int j = 0; j < 64; j++) acc += sm[8192 + tid * 64 + j] * c3w[j];
        out[tid] = acc;
    }
}

// ---------------------------------------------------------------------------
extern "C" void kernel_launch(void* const* d_in, const int* in_sizes, int n_in,
                              void* d_out, int out_size, void* d_ws, size_t ws_size,
                              hipStream_t stream) {
    (void)n_in; (void)out_size; (void)ws_size;
    const float* x      = (const float*)d_in[0];
    const int*   eidx   = (const int*)d_in[1];
    const int*   etype  = (const int*)d_in[2];
    const int*   batch  = (const int*)d_in[3];
    const float* proj_w = (const float*)d_in[4];
    const float* proj_b = (const float*)d_in[5];
    const float* ln0_w  = (const float*)d_in[6];
    const float* ln0_b  = (const float*)d_in[7];
    const float* ggnn_w = (const float*)d_in[8];
    const float* gwih   = (const float*)d_in[9];
    const float* gwhh   = (const float*)d_in[10];
    const float* gbih   = (const float*)d_in[11];
    const float* gbhh   = (const float*)d_in[12];
    const float* vln_w  = (const float*)d_in[13];
    const float* vln_b  = (const float*)d_in[14];
    const float* q_w    = (const float*)d_in[15];
    const float* q_b    = (const float*)d_in[16];
    const float* k_w    = (const float*)d_in[17];
    const float* k_b    = (const float*)d_in[18];
    const float* c1w    = (const float*)d_in[19];
    const float* c1b    = (const float*)d_in[20];
    const float* c2w    = (const float*)d_in[21];
    const float* c2b    = (const float*)d_in[22];
    const float* c3w    = (const float*)d_in[23];
    const float* c3b    = (const float*)d_in[24];
    float* out = (float*)d_out;

    const int N = in_sizes[3];
    const int E = in_sizes[2];
    const int IN = in_sizes[0] / N;
    const int H = 128, L = 4;
    const int N4 = 4 * N;

    long NH = (long)N * H;
    float* ws = (float*)d_ws;
    float* h0   = ws;                 // NH
    float* bufX = h0 + NH;            // 4*NH
    float* bufY = bufX + 4 * NH;      // 4*NH (S; Wcomb overlap at precompute)
    float* bufZ = bufY + 4 * NH;      // 4*NH (h ping-pong; P_ih/P_hh overlap)
    float* poolMean = bufZ + 4 * NH;  // 64*128
    float* poolMax  = poolMean + 64 * H;
    float* bp = poolMax + 64 * H;                  // 4*512
    short* Bp = (short*)(bp + 4 * 512);            // 16*131072 bf16
    int* iOff  = (int*)(Bp + 16 * 131072);         // N4+1
    int* iCnt  = iOff + N4 + 1;
    int* iCur  = iCnt + N4;
    int* iBsum = iCur + N4;                        // 256
    int* iEsrc = iBsum + 256;                      // E
    // precompute overlays (dead before layer loop starts)
    float* wcomb = bufY;              // 16*128*512 = 4 MB
    float* pih   = bufZ;              // 16*128*512
    float* phh   = bufZ + 16 * 65536; // 4*128*512

    int gx128 = (N + 127) / 128;
    int rb = (int)(((long)N * 32 + 255) / 256);
    int eb = (E + 255) / 256;
    int nbScan = (N4 + 1023) / 1024;

    const int* esrc_in = eidx;
    const int* edst_in = eidx + E;

    // ---- CSR build ----
    hipMemsetAsync(iCnt, 0, (size_t)N4 * sizeof(int), stream);
    count_k<<<eb, 256, 0, stream>>>(edst_in, etype, iCnt, E, N);
    scan1_k<<<nbScan, 256, 0, stream>>>(iCnt, iOff, iBsum, N4);
    scan2_k<<<1, 256, 0, stream>>>(iBsum, nbScan);
    scan3_k<<<(N4 + 255) / 256, 256, 0, stream>>>(iOff, iCur, iBsum, N4, E);
    fill_k<<<eb, 256, 0, stream>>>(esrc_in, edst_in, etype, iCur, iEsrc, E, N);

    // ---- GRU weight fold + bf16 pack (once per call) ----
    build_p_k<<<(16 * 65536 + 255) / 256, 256, 0, stream>>>(
        gwih, gwhh, gbih, gbhh, pih, phh, bp);
    // Wcomb[z] = ggnn_w[z] (128x128) @ P_ih_rep[z] (128x512), z = v*4+i
    gemm_k<false, 0><<<dim3(1, 4, 16), 256, 0, stream>>>(
        ggnn_w, pih, nullptr, wcomb, 128, 512, 128,
        (long)H * H, 65536, 65536);
    pack_b_k<<<(16 * 256 * 512 + 255) / 256, 256, 0, stream>>>(wcomb, phh, Bp);

    // ---- input projection + LN + GELU + broadcast ----
    gemm_k<false, 0><<<dim3(gx128, 1, 1), 256, 0, stream>>>(
        x, proj_w, proj_b, h0, N, H, IN, 0, 0, 0);
    ln_gelu_k<<<rb, 256, 0, stream>>>(h0, ln0_w, ln0_b, N);
    bcast4_k<<<(int)((NH / 4 + 255) / 256), 256, 0, stream>>>(
        (const float4*)h0, (float4*)bufX, NH / 4);

    // ---- 4 GGNN layers: gather(h) -> fused MFMA GRU ----
    int gx64 = (N + 63) / 64;
    float* hcur = bufX;
    for (int i = 0; i < L; i++) {
        gather_k<<<(int)(((long)N4 * 32 + 255) / 256), 256, 0, stream>>>(
            hcur, bufY, iOff, iEsrc, N4);
        float* hnxt = (hcur == bufX) ? bufZ : bufX;
        gemm_gru_mfma_k<<<dim3(gx64, 2, 4), 256, 0, stream>>>(
            bufY, hcur, Bp + (long)i * 131072, bp, hnxt, N, NH);
        hcur = hnxt;
    }

    // ---- per-view LN + residual (hcur becomes hs) ----
    vln_res_k<<<dim3(rb, 1, 4), 256, 0, stream>>>(hcur, h0, vln_w, vln_b, N);

    // ---- attention + fusion + pooling + classifier ----
    float* q = bufY;
    float* u = bufY + NH;
    float* fused = bufY + 2 * NH;
    gemm_k<false, 1><<<dim3(gx128, 1, 1), 256, 0, stream>>>(
        h0, q_w, q_b, q, N, H, H, 0, 0, 0);
    gemm_k<true, 0><<<dim3(gx128, 1, 1), 256, 0, stream>>>(
        q, k_w, nullptr, u, N, H, H, 0, 0, 0);
    fusion_k<<<rb, 256, 0, stream>>>(hcur, q, u, k_b, fused, N);
    pool_k<<<64, 256, 0, stream>>>(fused, batch, poolMean, poolMax, N);
    classifier_k<<<1, 256, 0, stream>>>(
        poolMean, poolMax, c1w, c1b, c2w, c2b, c3w, c3b, out);
}

// Round 5
// 1989.398 us; speedup vs baseline: 4.2729x; 1.0458x over previous
//
#include <hip/hip_runtime.h>
#include <math.h>

// ---------------------------------------------------------------------------
// MultiViewEPSSClassifier forward. N=50000, E=600000, IN=512, H=128, B=64, L=4.
// R2: atomic scatter -> CSR gather.   R3: atomic-free pooling; fused GRU GEMM.
// R4: ggnn_w folded into GRU weights; GRU GEMM -> MFMA bf16 (A hi/lo 2-pass).
// R5: (a) classifier 1 block -> 64 blocks (was 273us latency-bound on 1 CU);
//     (b) proj/q/u GEMMs -> MFMA 3-pass (A hi/lo x B hi/lo packed);
//     (c) bcast4 deleted (layer-0 reads h0 via esrc0 + view-stride 0);
//     (d) GRU kernel: B staged direct from L2 (no LDS), LDS 30.7->10.2 KB.
// ---------------------------------------------------------------------------

typedef __attribute__((ext_vector_type(8))) short short8;
typedef __attribute__((ext_vector_type(4))) float floatx4;

__device__ __forceinline__ unsigned short f2bf_rtn(float x) {
    unsigned u = __float_as_uint(x);
    return (unsigned short)((u + 0x7FFFu + ((u >> 16) & 1u)) >> 16);
}

// types {0,9,10}->0, {1,2,3}->1, {4,5,6}->2, {7,8,11,12}->3 (partition of 0..12)
__device__ __forceinline__ int view_of(int t) {
    return (t >= 1 && t <= 3) ? 1 : (t >= 4 && t <= 6) ? 2
         : ((t == 7) || (t == 8) || (t >= 11)) ? 3 : 0;
}

// ----------------- fp32 GEMM (Wcomb precompute only, tiny) -----------------
template <bool BT, int EPI>
__global__ __launch_bounds__(256, 2) void gemm_k(
    const float* __restrict__ A, const float* __restrict__ Bm,
    const float* __restrict__ bias, float* __restrict__ C,
    int N, int M, int K, long sA, long sB, long sC)
{
    __shared__ float As[32][132];
    __shared__ float Bs[32][132];
    A  += (long)blockIdx.z * sA;
    Bm += (long)blockIdx.z * sB;
    C  += (long)blockIdx.z * sC;
    const int r0 = blockIdx.x * 128;
    const int c0 = blockIdx.y * 128;
    const int tid = threadIdx.x;
    const int tx = tid & 15;
    const int ty = tid >> 4;

    float acc[8][8];
#pragma unroll
    for (int i = 0; i < 8; i++)
#pragma unroll
        for (int j = 0; j < 8; j++) acc[i][j] = 0.0f;

    for (int k0 = 0; k0 < K; k0 += 32) {
        {
            int arow = tid >> 3;
            int akq  = (tid & 7) << 2;
#pragma unroll
            for (int hh = 0; hh < 4; hh++) {
                int r  = arow + hh * 32;
                int gr = r0 + r;
                float4 av = make_float4(0.f, 0.f, 0.f, 0.f);
                if (gr < N) av = *(const float4*)(A + (long)gr * K + k0 + akq);
                As[akq + 0][r] = av.x; As[akq + 1][r] = av.y;
                As[akq + 2][r] = av.z; As[akq + 3][r] = av.w;
            }
        }
        if (BT) {
            int brow = tid >> 3;
            int bkq  = (tid & 7) << 2;
#pragma unroll
            for (int hh = 0; hh < 4; hh++) {
                int r = brow + hh * 32;
                float4 bv = *(const float4*)(Bm + (long)(c0 + r) * K + k0 + bkq);
                Bs[bkq + 0][r] = bv.x; Bs[bkq + 1][r] = bv.y;
                Bs[bkq + 2][r] = bv.z; Bs[bkq + 3][r] = bv.w;
            }
        } else {
            int kk0 = tid >> 5;
            int bmq = (tid & 31) << 2;
#pragma unroll
            for (int hh = 0; hh < 4; hh++) {
                int kk = kk0 + hh * 8;
                float4 bv = *(const float4*)(Bm + (long)(k0 + kk) * M + c0 + bmq);
                *(float4*)&Bs[kk][bmq] = bv;
            }
        }
        __syncthreads();
#pragma unroll
        for (int k = 0; k < 32; k++) {
            float4 a0 = *(const float4*)&As[k][ty << 2];
            float4 a1 = *(const float4*)&As[k][64 + (ty << 2)];
            float4 b0 = *(const float4*)&Bs[k][tx << 2];
            float4 b1 = *(const float4*)&Bs[k][64 + (tx << 2)];
            float av[8] = {a0.x, a0.y, a0.z, a0.w, a1.x, a1.y, a1.z, a1.w};
            float bv[8] = {b0.x, b0.y, b0.z, b0.w, b1.x, b1.y, b1.z, b1.w};
#pragma unroll
            for (int i = 0; i < 8; i++)
#pragma unroll
                for (int j = 0; j < 8; j++) acc[i][j] += av[i] * bv[j];
        }
        __syncthreads();
    }

    float bb[8] = {0, 0, 0, 0, 0, 0, 0, 0};
    if (bias) {
        float4 b0 = *(const float4*)(bias + c0 + (tx << 2));
        float4 b1 = *(const float4*)(bias + c0 + 64 + (tx << 2));
        bb[0] = b0.x; bb[1] = b0.y; bb[2] = b0.z; bb[3] = b0.w;
        bb[4] = b1.x; bb[5] = b1.y; bb[6] = b1.z; bb[7] = b1.w;
    }
#pragma unroll
    for (int i = 0; i < 8; i++) {
        int r = (i < 4) ? (r0 + (ty << 2) + i) : (r0 + 64 + (ty << 2) + i - 4);
        if (r < N) {
            float v[8];
#pragma unroll
            for (int j = 0; j < 8; j++) {
                v[j] = acc[i][j] + bb[j];
                if (EPI == 1) v[j] = tanhf(v[j]);
            }
            *(float4*)(C + (long)r * M + c0 + (tx << 2)) = make_float4(v[0], v[1], v[2], v[3]);
            *(float4*)(C + (long)r * M + c0 + 64 + (tx << 2)) = make_float4(v[4], v[5], v[6], v[7]);
        }
    }
}

// ---------- build P_ih_rep[16][128][512], P_hh[4][128][512], bias ----------
__global__ __launch_bounds__(256) void build_p_k(
    const float* __restrict__ gwih, const float* __restrict__ gwhh,
    const float* __restrict__ gbih, const float* __restrict__ gbhh,
    float* __restrict__ pih, float* __restrict__ phh, float* __restrict__ bp)
{
    int idx = blockIdx.x * 256 + threadIdx.x;
    if (idx < 16 * 65536) {
        int z = idx >> 16, rem = idx & 65535;
        int k = rem >> 9, mcol = rem & 511;
        int ch = mcol >> 2, g = mcol & 3;
        int v = z >> 2;
        const float* Wih = gwih + (long)v * 384 * 128;
        float val = 0.0f;
        if (g == 0) val = Wih[ch * 128 + k];
        else if (g == 1) val = Wih[(128 + ch) * 128 + k];
        else if (g == 2) val = Wih[(256 + ch) * 128 + k];
        pih[idx] = val;
    }
    if (idx < 4 * 65536) {
        int v = idx >> 16, rem = idx & 65535;
        int k = rem >> 9, mcol = rem & 511;
        int ch = mcol >> 2, g = mcol & 3;
        const float* Whh = gwhh + (long)v * 384 * 128;
        float val = 0.0f;
        if (g == 0) val = Whh[ch * 128 + k];
        else if (g == 1) val = Whh[(128 + ch) * 128 + k];
        else if (g == 3) val = Whh[(256 + ch) * 128 + k];
        phh[idx] = val;
    }
    if (idx < 4 * 512) {
        int v = idx >> 9, mcol = idx & 511;
        int ch = mcol >> 2, g = mcol & 3;
        float val;
        if (g == 0) val = gbih[v * 384 + ch] + gbhh[v * 384 + ch];
        else if (g == 1) val = gbih[v * 384 + 128 + ch] + gbhh[v * 384 + 128 + ch];
        else if (g == 2) val = gbih[v * 384 + 256 + ch];
        else val = gbhh[v * 384 + 256 + ch];
        bp[idx] = val;
    }
}

// ---- pack combined GRU weights -> bf16 frag order [z][ks][col][q*8+j] -----
__global__ __launch_bounds__(256) void pack_b_k(
    const float* __restrict__ wcomb, const float* __restrict__ phh,
    short* __restrict__ Bp)
{
    int idx = blockIdx.x * 256 + threadIdx.x;
    if (idx >= 16 * 256 * 512) return;
    int z = idx >> 17, rem = idx & 131071;
    int k = rem >> 9, col = rem & 511;
    float val = (k < 128) ? wcomb[(long)z * 65536 + k * 512 + col]
                          : phh[(long)(z >> 2) * 65536 + (k - 128) * 512 + col];
    long dst = ((long)(z * 8 + (k >> 5)) * 512 + col) * 32 + ((k >> 3) & 3) * 8 + (k & 7);
    Bp[dst] = (short)f2bf_rtn(val);
}

// ---- pack fp32 weight [K][128] (or transposed [128][K]) -> bf16 hi/lo -----
template <bool BT>
__global__ __launch_bounds__(256) void pack_w_k(
    const float* __restrict__ W, short* __restrict__ bhi, short* __restrict__ blo, int K)
{
    int idx = blockIdx.x * 256 + threadIdx.x;
    if (idx >= K * 128) return;
    int k = idx >> 7, col = idx & 127;
    float v = BT ? W[col * K + k] : W[k * 128 + col];
    unsigned short h = f2bf_rtn(v);
    float fh = __uint_as_float((unsigned)h << 16);
    long dst = ((long)(k >> 5) * 128 + col) * 32 + ((k >> 3) & 3) * 8 + (k & 7);
    bhi[dst] = (short)h;
    blo[dst] = (short)f2bf_rtn(v - fh);
}

// ------------- MFMA GEMM: C[N,128] = A[N,K]@W + bias, 3-pass ---------------
// Block 64 rows; wave w -> 16 rows x 128 cols. B frags direct from L2.
template <int EPI>
__global__ __launch_bounds__(256, 4) void gemm_mfma_k(
    const float* __restrict__ A, const short* __restrict__ Bhi,
    const short* __restrict__ Blo, const float* __restrict__ bias,
    float* __restrict__ C, int N, int K)
{
    __shared__ __align__(16) short Ahi[64 * 40];
    __shared__ __align__(16) short Alo[64 * 40];
    const int r0 = blockIdx.x * 64;
    const int tid = threadIdx.x;
    const int l = tid & 63, w = tid >> 6;
    const int wrow = w * 16;
    const int m = l & 15, q = l >> 4;

    floatx4 acc[8];
#pragma unroll
    for (int b = 0; b < 8; b++) acc[b] = (floatx4)0.0f;

    const int arow = tid >> 2;
    const int fcol = (tid & 3) * 8;
    const int gr = r0 + arow;
    const int nks = K >> 5;

    for (int ks = 0; ks < nks; ks++) {
        float xv[8];
        if (gr < N) {
            float4 x0 = *(const float4*)(A + (long)gr * K + ks * 32 + fcol);
            float4 x1 = *(const float4*)(A + (long)gr * K + ks * 32 + fcol + 4);
            xv[0] = x0.x; xv[1] = x0.y; xv[2] = x0.z; xv[3] = x0.w;
            xv[4] = x1.x; xv[5] = x1.y; xv[6] = x1.z; xv[7] = x1.w;
        } else {
#pragma unroll
            for (int u = 0; u < 8; u++) xv[u] = 0.0f;
        }
        short8 vhi, vlo;
#pragma unroll
        for (int u = 0; u < 8; u++) {
            unsigned short hb = f2bf_rtn(xv[u]);
            float fh = __uint_as_float((unsigned)hb << 16);
            vhi[u] = (short)hb;
            vlo[u] = (short)f2bf_rtn(xv[u] - fh);
        }
        *(short8*)&Ahi[arow * 40 + fcol] = vhi;
        *(short8*)&Alo[arow * 40 + fcol] = vlo;
        __syncthreads();
        short8 ah = *(short8*)&Ahi[(wrow + m) * 40 + q * 8];
        short8 al = *(short8*)&Alo[(wrow + m) * 40 + q * 8];
#pragma unroll
        for (int tn = 0; tn < 8; tn++) {
            int col = tn * 16 + m;
            short8 bh = *(const short8*)(Bhi + ((long)ks * 128 + col) * 32 + q * 8);
            short8 bl = *(const short8*)(Blo + ((long)ks * 128 + col) * 32 + q * 8);
            acc[tn] = __builtin_amdgcn_mfma_f32_16x16x32_bf16(ah, bh, acc[tn], 0, 0, 0);
            acc[tn] = __builtin_amdgcn_mfma_f32_16x16x32_bf16(al, bh, acc[tn], 0, 0, 0);
            acc[tn] = __builtin_amdgcn_mfma_f32_16x16x32_bf16(ah, bl, acc[tn], 0, 0, 0);
        }
        __syncthreads();
    }

#pragma unroll
    for (int tn = 0; tn < 8; tn++) {
        int col = tn * 16 + m;
        float bb = bias ? bias[col] : 0.0f;
#pragma unroll
        for (int reg = 0; reg < 4; reg++) {
            int row = r0 + wrow + q * 4 + reg;
            if (row < N) {
                float v = acc[tn][reg] + bb;
                if (EPI == 1) v = tanhf(v);
                C[(long)row * 128 + col] = v;
            }
        }
    }
}

// -------------- MFMA fused GRU GEMM: h_next = GRU(S, h_cur) ----------------
// C-space [N x 512] per view (cols = ch*4+gate), K=256 over [S|h].
// Block 64r x 256c; 4 waves of 32r x 128c. A: fp32->bf16 hi/lo (2-pass).
// B: bf16 frags direct from L2 (pre-packed). sHc=0 => all views read h0.
__global__ __launch_bounds__(256, 3) void gemm_gru_mfma_k(
    const float* __restrict__ S, const float* __restrict__ hcur,
    const short* __restrict__ Bp, const float* __restrict__ bp,
    float* __restrict__ hnext, int N, long sA, long sHc)
{
    __shared__ __align__(16) short Ahi[64 * 40];
    __shared__ __align__(16) short Alo[64 * 40];
    const int z = blockIdx.z;
    S     += (long)z * sA;
    hcur  += (long)z * sHc;
    Bp    += (long)z * 524288;
    bp    += (long)z * 512;
    hnext += (long)z * sA;
    const int r0  = blockIdx.x * 64;
    const int c0b = blockIdx.y * 256;
    const int tid = threadIdx.x;
    const int l = tid & 63, w = tid >> 6;
    const int wrow = (w & 1) * 32, wcol = (w >> 1) * 128;
    const int m = l & 15, q = l >> 4;

    floatx4 acc[2][8];
#pragma unroll
    for (int a = 0; a < 2; a++)
#pragma unroll
        for (int b = 0; b < 8; b++) acc[a][b] = (floatx4)0.0f;

    const int arow = tid >> 2;
    const int fcol = (tid & 3) * 8;
    const int gr = r0 + arow;

    for (int ks = 0; ks < 8; ks++) {
        const float* Asrc = (ks < 4) ? S : hcur;
        const int kc = (ks & 3) * 32 + fcol;
        float xv[8];
        if (gr < N) {
            float4 x0 = *(const float4*)(Asrc + (long)gr * 128 + kc);
            float4 x1 = *(const float4*)(Asrc + (long)gr * 128 + kc + 4);
            xv[0] = x0.x; xv[1] = x0.y; xv[2] = x0.z; xv[3] = x0.w;
            xv[4] = x1.x; xv[5] = x1.y; xv[6] = x1.z; xv[7] = x1.w;
        } else {
#pragma unroll
            for (int u = 0; u < 8; u++) xv[u] = 0.0f;
        }
        short8 vhi, vlo;
#pragma unroll
        for (int u = 0; u < 8; u++) {
            unsigned short hb = f2bf_rtn(xv[u]);
            float fh = __uint_as_float((unsigned)hb << 16);
            vhi[u] = (short)hb;
            vlo[u] = (short)f2bf_rtn(xv[u] - fh);
        }
        *(short8*)&Ahi[arow * 40 + fcol] = vhi;
        *(short8*)&Alo[arow * 40 + fcol] = vlo;
        __syncthreads();
        short8 a_hi0 = *(short8*)&Ahi[(wrow + m) * 40 + q * 8];
        short8 a_lo0 = *(short8*)&Alo[(wrow + m) * 40 + q * 8];
        short8 a_hi1 = *(short8*)&Ahi[(wrow + 16 + m) * 40 + q * 8];
        short8 a_lo1 = *(short8*)&Alo[(wrow + 16 + m) * 40 + q * 8];
#pragma unroll
        for (int tn = 0; tn < 8; tn++) {
            int col = c0b + wcol + tn * 16 + m;
            short8 bf = *(const short8*)(Bp + ((long)ks * 512 + col) * 32 + q * 8);
            acc[0][tn] = __builtin_amdgcn_mfma_f32_16x16x32_bf16(a_hi0, bf, acc[0][tn], 0, 0, 0);
            acc[0][tn] = __builtin_amdgcn_mfma_f32_16x16x32_bf16(a_lo0, bf, acc[0][tn], 0, 0, 0);
            acc[1][tn] = __builtin_amdgcn_mfma_f32_16x16x32_bf16(a_hi1, bf, acc[1][tn], 0, 0, 0);
            acc[1][tn] = __builtin_amdgcn_mfma_f32_16x16x32_bf16(a_lo1, bf, acc[1][tn], 0, 0, 0);
        }
        __syncthreads();
    }

    // ---- GRU epilogue: quad (4 gate cols) -> per-lane row via shuffles ----
    const int g = l & 3;
    const int q0 = l & ~3;
#pragma unroll
    for (int tm = 0; tm < 2; tm++) {
        const int row = r0 + wrow + tm * 16 + q * 4 + g;
#pragma unroll
        for (int tn = 0; tn < 8; tn++) {
            floatx4 a = acc[tm][tn];
            float vr = 0.f, vz = 0.f, vn = 0.f, vh = 0.f;
#pragma unroll
            for (int i = 0; i < 4; i++) {
                float t0 = __shfl(a[i], q0 + 0);
                float t1 = __shfl(a[i], q0 + 1);
                float t2 = __shfl(a[i], q0 + 2);
                float t3 = __shfl(a[i], q0 + 3);
                if (g == i) { vr = t0; vz = t1; vn = t2; vh = t3; }
            }
            const int colq = c0b + wcol + tn * 16 + (m & ~3);
            if (row < N) {
                float4 bv = *(const float4*)(bp + colq);
                int ch = colq >> 2;
                float hp = hcur[(long)row * 128 + ch];
                float rr = 1.0f / (1.0f + expf(-(vr + bv.x)));
                float zz = 1.0f / (1.0f + expf(-(vz + bv.y)));
                float nn = tanhf(vn + bv.z + rr * (vh + bv.w));
                hnext[(long)row * 128 + ch] = (1.0f - zz) * nn + zz * hp;
            }
        }
    }
}

// ----------------------- LayerNorm + GELU (in-place) -----------------------
__global__ __launch_bounds__(256) void ln_gelu_k(
    float* __restrict__ h0, const float* __restrict__ w, const float* __restrict__ b, int N)
{
    long t = (long)blockIdx.x * 256 + threadIdx.x;
    int n = (int)(t >> 5), lane = (int)(t & 31);
    if (n >= N) return;
    float* p = h0 + (long)n * 128 + lane * 4;
    float4 x = *(float4*)p;
    float s = x.x + x.y + x.z + x.w;
#pragma unroll
    for (int off = 16; off >= 1; off >>= 1) s += __shfl_xor(s, off);
    float mu = s * (1.0f / 128.0f);
    float4 d = make_float4(x.x - mu, x.y - mu, x.z - mu, x.w - mu);
    float ss = d.x * d.x + d.y * d.y + d.z * d.z + d.w * d.w;
#pragma unroll
    for (int off = 16; off >= 1; off >>= 1) ss += __shfl_xor(ss, off);
    float inv = 1.0f / sqrtf(ss * (1.0f / 128.0f) + 1e-5f);
    float4 wv = *(const float4*)(w + lane * 4);
    float4 bv = *(const float4*)(b + lane * 4);
    float y[4] = {d.x * inv * wv.x + bv.x, d.y * inv * wv.y + bv.y,
                  d.z * inv * wv.z + bv.z, d.w * inv * wv.w + bv.w};
#pragma unroll
    for (int i = 0; i < 4; i++)
        y[i] = 0.5f * y[i] * (1.0f + erff(y[i] * 0.70710678118654752f));
    *(float4*)p = make_float4(y[0], y[1], y[2], y[3]);
}

// ------------------------------ CSR build ----------------------------------
__global__ __launch_bounds__(256) void count_k(
    const int* __restrict__ dst, const int* __restrict__ et,
    int* __restrict__ cnt, int E, int N)
{
    int e = blockIdx.x * 256 + threadIdx.x;
    if (e >= E) return;
    int v = view_of(et[e]);
    atomicAdd(&cnt[v * N + dst[e]], 1);
}

__global__ __launch_bounds__(256) void scan1_k(
    const int* __restrict__ cnt, int* __restrict__ off, int* __restrict__ bsum, int n)
{
    __shared__ int sm[256];
    int base = blockIdx.x * 1024;
    int tid = threadIdx.x;
    int v[4]; int s = 0;
#pragma unroll
    for (int i = 0; i < 4; i++) {
        int idx = base + tid * 4 + i;
        v[i] = (idx < n) ? cnt[idx] : 0; s += v[i];
    }
    sm[tid] = s; __syncthreads();
    for (int o = 1; o < 256; o <<= 1) {
        int t2 = (tid >= o) ? sm[tid - o] : 0;
        __syncthreads(); sm[tid] += t2; __syncthreads();
    }
    int run = sm[tid] - s;
    if (tid == 255) bsum[blockIdx.x] = sm[255];
#pragma unroll
    for (int i = 0; i < 4; i++) {
        int idx = base + tid * 4 + i;
        if (idx < n) off[idx] = run;
        run += v[i];
    }
}

__global__ __launch_bounds__(256) void scan2_k(int* __restrict__ bsum, int nb)
{
    __shared__ int sm[256];
    int tid = threadIdx.x;
    int v = (tid < nb) ? bsum[tid] : 0;
    sm[tid] = v; __syncthreads();
    for (int o = 1; o < 256; o <<= 1) {
        int t2 = (tid >= o) ? sm[tid - o] : 0;
        __syncthreads(); sm[tid] += t2; __syncthreads();
    }
    if (tid < nb) bsum[tid] = sm[tid] - v;
}

__global__ __launch_bounds__(256) void scan3_k(
    int* __restrict__ off, int* __restrict__ cursor,
    const int* __restrict__ bsum, int n, int total)
{
    int i = blockIdx.x * 256 + threadIdx.x;
    if (i < n) {
        int o = off[i] + bsum[i >> 10];
        off[i] = o; cursor[i] = o;
    }
    if (i == 0) off[n] = total;
}

__global__ __launch_bounds__(256) void fill_k(
    const int* __restrict__ src, const int* __restrict__ dst,
    const int* __restrict__ et, int* __restrict__ cursor,
    int* __restrict__ esrc, int* __restrict__ esrc0, int E, int N)
{
    int e = blockIdx.x * 256 + threadIdx.x;
    if (e >= E) return;
    int v = view_of(et[e]);
    int b = v * N + dst[e];
    int pos = atomicAdd(&cursor[b], 1);
    esrc[pos] = v * N + src[e];
    esrc0[pos] = src[e];
}

// -------------------- CSR gather: S[r] = sum m[esrc[j]] --------------------
__global__ __launch_bounds__(256) void gather_k(
    const float* __restrict__ m, float* __restrict__ agg,
    const int* __restrict__ off, const int* __restrict__ esrc, int R)
{
    long t = (long)blockIdx.x * 256 + threadIdx.x;
    int r = (int)(t >> 5), lane = (int)(t & 31);
    if (r >= R) return;
    int beg = off[r], end = off[r + 1];
    float4 acc = make_float4(0.f, 0.f, 0.f, 0.f);
    for (int j = beg; j < end; j++) {
        int s = esrc[j];
        float4 mv = *(const float4*)(m + (long)s * 128 + lane * 4);
        acc.x += mv.x; acc.y += mv.y; acc.z += mv.z; acc.w += mv.w;
    }
    *(float4*)(agg + (long)r * 128 + lane * 4) = acc;
}

// -------------------- per-view LayerNorm + residual (in-place) -------------
__global__ __launch_bounds__(256) void vln_res_k(
    float* __restrict__ h, const float* __restrict__ h0,
    const float* __restrict__ w, const float* __restrict__ b, int N)
{
    int v = blockIdx.z;
    long t = (long)blockIdx.x * 256 + threadIdx.x;
    int n = (int)(t >> 5), lane = (int)(t & 31);
    if (n >= N) return;
    float* hp = h + ((long)v * N + n) * 128 + lane * 4;
    float4 x = *(float4*)hp;
    float s = x.x + x.y + x.z + x.w;
#pragma unroll
    for (int off = 16; off >= 1; off >>= 1) s += __shfl_xor(s, off);
    float mu = s * (1.0f / 128.0f);
    float4 d = make_float4(x.x - mu, x.y - mu, x.z - mu, x.w - mu);
    float ss = d.x * d.x + d.y * d.y + d.z * d.z + d.w * d.w;
#pragma unroll
    for (int off = 16; off >= 1; off >>= 1) ss += __shfl_xor(ss, off);
    float inv = 1.0f / sqrtf(ss * (1.0f / 128.0f) + 1e-5f);
    float4 wv = *(const float4*)(w + v * 128 + lane * 4);
    float4 bv = *(const float4*)(b + v * 128 + lane * 4);
    float4 hv = *(const float4*)(h0 + (long)n * 128 + lane * 4);
    float4 r;
    r.x = d.x * inv * wv.x + bv.x + hv.x;
    r.y = d.y * inv * wv.y + bv.y + hv.y;
    r.z = d.z * inv * wv.z + bv.z + hv.z;
    r.w = d.w * inv * wv.w + bv.w + hv.w;
    *(float4*)hp = r;
}

// -------------- attention fusion (no atomics): fused[N,128] ----------------
__global__ __launch_bounds__(256) void fusion_k(
    const float* __restrict__ hs, const float* __restrict__ q,
    const float* __restrict__ u, const float* __restrict__ kb,
    float* __restrict__ fused, int N)
{
    long t = (long)blockIdx.x * 256 + threadIdx.x;
    int n = (int)(t >> 5), lane = (int)(t & 31);
    if (n >= N) return;
    long NH = (long)N * 128;
    float4 qv = *(const float4*)(q + (long)n * 128 + lane * 4);
    float4 kv = *(const float4*)(kb + lane * 4);
    float4 uv = *(const float4*)(u + (long)n * 128 + lane * 4);
    float part = qv.x * kv.x + qv.y * kv.y + qv.z * kv.z + qv.w * kv.w;
    float4 hv[4];
    float lg[4];
#pragma unroll
    for (int v = 0; v < 4; v++) {
        hv[v] = *(const float4*)(hs + v * NH + (long)n * 128 + lane * 4);
        lg[v] = hv[v].x * uv.x + hv[v].y * uv.y + hv[v].z * uv.z + hv[v].w * uv.w;
    }
#pragma unroll
    for (int off = 16; off >= 1; off >>= 1) {
        part += __shfl_xor(part, off);
#pragma unroll
        for (int v = 0; v < 4; v++) lg[v] += __shfl_xor(lg[v], off);
    }
    const float scale = 0.08838834764831845f;
    float mx = -1e30f;
#pragma unroll
    for (int v = 0; v < 4; v++) { lg[v] = (lg[v] + part) * scale; mx = fmaxf(mx, lg[v]); }
    float se = 0.0f;
#pragma unroll
    for (int v = 0; v < 4; v++) { lg[v] = expf(lg[v] - mx); se += lg[v]; }
    float inv = 1.0f / se;
    float4 f = make_float4(0.f, 0.f, 0.f, 0.f);
#pragma unroll
    for (int v = 0; v < 4; v++) {
        float a = lg[v] * inv;
        f.x += a * hv[v].x; f.y += a * hv[v].y; f.z += a * hv[v].z; f.w += a * hv[v].w;
    }
    *(float4*)(fused + (long)n * 128 + lane * 4) = f;
}

// ------------- pooling: one block per graph (batch is sorted) --------------
__global__ __launch_bounds__(256) void pool_k(
    const float* __restrict__ fused, const int* __restrict__ batch,
    float* __restrict__ meanb, float* __restrict__ maxb, int N)
{
    __shared__ float s_sum[256], s_max[256];
    int b = blockIdx.x;
    int lo = 0, hi = N;
    while (lo < hi) { int mid = (lo + hi) >> 1; if (batch[mid] < b) lo = mid + 1; else hi = mid; }
    int beg = lo;
    lo = beg; hi = N;
    while (lo < hi) { int mid = (lo + hi) >> 1; if (batch[mid] < b + 1) lo = mid + 1; else hi = mid; }
    int end = lo;
    int tid = threadIdx.x;
    int c = tid & 127, half = tid >> 7;
    float sum = 0.0f, mx = __int_as_float(0xff800000);
    for (int n = beg + half; n < end; n += 2) {
        float v = fused[(long)n * 128 + c];
        sum += v; mx = fmaxf(mx, v);
    }
    s_sum[tid] = sum; s_max[tid] = mx;
    __syncthreads();
    if (half == 0) {
        float tot = s_sum[tid] + s_sum[tid + 128];
        float m2 = fmaxf(s_max[tid], s_max[tid + 128]);
        int cnt = end - beg;
        meanb[b * 128 + c] = tot / (float)max(cnt, 1);
        maxb[b * 128 + c] = m2;
    }
}

// ---------------- classifier MLP: one block per graph (64 blocks) ----------
__global__ __launch_bounds__(256) void classifier_k(
    const float* __restrict__ meanb, const float* __restrict__ maxb,
    const float* __restrict__ c1w, const float* __restrict__ c1b,
    const float* __restrict__ c2w, const float* __restrict__ c2b,
    const float* __restrict__ c3w, const float* __restrict__ c3b,
    float* __restrict__ out)
{
    __shared__ float g[256];
    __shared__ float h1[128];
    __shared__ float h2[64];
    int b = blockIdx.x, tid = threadIdx.x;
    g[tid] = (tid < 128) ? meanb[b * 128 + tid] : maxb[b * 128 + (tid - 128)];
    __syncthreads();
    if (tid < 128) {
        float acc = c1b[tid];
        for (int k = 0; k < 256; k++) acc += g[k] * c1w[k * 128 + tid];
        h1[tid] = fmaxf(acc, 0.0f);
    }
    __syncthreads();
    if (tid < 64) {
        float acc = c2b[tid];
        for (int k = 0; k < 128; k++) acc += h1[k] * c2w[k * 64 + tid];
        h2[tid] = fmaxf(acc, 0.0f);
    }
    __syncthreads();
    if (tid < 64) {
        float p = h2[tid] * c3w[tid];
#pragma unroll
        for (int off = 32; off >= 1; off >>= 1) p += __shfl_xor(p, off);
        if (tid == 0) out[b] = c3b[0] + p;
    }
}

// ---------------------------------------------------------------------------
extern "C" void kernel_launch(void* const* d_in, const int* in_sizes, int n_in,
                              void* d_out, int out_size, void* d_ws, size_t ws_size,
                              hipStream_t stream) {
    (void)n_in; (void)out_size; (void)ws_size;
    const float* x      = (const float*)d_in[0];
    const int*   eidx   = (const int*)d_in[1];
    const int*   etype  = (const int*)d_in[2];
    const int*   batch  = (const int*)d_in[3];
    const float* proj_w = (const float*)d_in[4];
    const float* proj_b = (const float*)d_in[5];
    const float* ln0_w  = (const float*)d_in[6];
    const float* ln0_b  = (const float*)d_in[7];
    const float* ggnn_w = (const float*)d_in[8];
    const float* gwih   = (const float*)d_in[9];
    const float* gwhh   = (const float*)d_in[10];
    const float* gbih   = (const float*)d_in[11];
    const float* gbhh   = (const float*)d_in[12];
    const float* vln_w  = (const float*)d_in[13];
    const float* vln_b  = (const float*)d_in[14];
    const float* q_w    = (const float*)d_in[15];
    const float* q_b    = (const float*)d_in[16];
    const float* k_w    = (const float*)d_in[17];
    const float* k_b    = (const float*)d_in[18];
    const float* c1w    = (const float*)d_in[19];
    const float* c1b    = (const float*)d_in[20];
    const float* c2w    = (const float*)d_in[21];
    const float* c2b    = (const float*)d_in[22];
    const float* c3w    = (const float*)d_in[23];
    const float* c3b    = (const float*)d_in[24];
    float* out = (float*)d_out;

    const int N = in_sizes[3];
    const int E = in_sizes[2];
    const int IN = in_sizes[0] / N;
    const int H = 128, L = 4;
    const int N4 = 4 * N;

    long NH = (long)N * H;
    float* ws = (float*)d_ws;
    float* h0   = ws;                 // NH
    float* bufX = h0 + NH;            // 4*NH (h ping-pong)
    float* bufY = bufX + 4 * NH;      // 4*NH (S; Wcomb overlay at precompute)
    float* bufZ = bufY + 4 * NH;      // 4*NH (h ping-pong; P_ih/P_hh overlay)
    float* poolMean = bufZ + 4 * NH;  // 64*128
    float* poolMax  = poolMean + 64 * H;
    float* bp = poolMax + 64 * H;                  // 4*512
    short* Bp = (short*)(bp + 4 * 512);            // 16*131072
    short* prjHi = Bp + 16 * 131072;               // 512*128
    short* prjLo = prjHi + 512 * 128;
    short* qwHi  = prjLo + 512 * 128;              // 128*128
    short* qwLo  = qwHi + 128 * 128;
    short* kwHi  = qwLo + 128 * 128;
    short* kwLo  = kwHi + 128 * 128;
    int* iOff  = (int*)(kwLo + 128 * 128);         // N4+1
    int* iCnt  = iOff + N4 + 1;
    int* iCur  = iCnt + N4;
    int* iBsum = iCur + N4;                        // 256
    int* iEsrc  = iBsum + 256;                     // E
    int* iEsrc0 = iEsrc + E;                       // E
    // precompute overlays (dead before layer loop starts)
    float* wcomb = bufY;              // 16*128*512
    float* pih   = bufZ;              // 16*128*512
    float* phh   = bufZ + 16 * 65536; // 4*128*512

    int rb = (int)(((long)N * 32 + 255) / 256);
    int eb = (E + 255) / 256;
    int nbScan = (N4 + 1023) / 1024;
    int gx64 = (N + 63) / 64;

    const int* esrc_in = eidx;
    const int* edst_in = eidx + E;

    // ---- CSR build ----
    hipMemsetAsync(iCnt, 0, (size_t)N4 * sizeof(int), stream);
    count_k<<<eb, 256, 0, stream>>>(edst_in, etype, iCnt, E, N);
    scan1_k<<<nbScan, 256, 0, stream>>>(iCnt, iOff, iBsum, N4);
    scan2_k<<<1, 256, 0, stream>>>(iBsum, nbScan);
    scan3_k<<<(N4 + 255) / 256, 256, 0, stream>>>(iOff, iCur, iBsum, N4, E);
    fill_k<<<eb, 256, 0, stream>>>(esrc_in, edst_in, etype, iCur, iEsrc, iEsrc0, E, N);

    // ---- GRU weight fold + bf16 packs (once per call) ----
    build_p_k<<<(16 * 65536 + 255) / 256, 256, 0, stream>>>(
        gwih, gwhh, gbih, gbhh, pih, phh, bp);
    gemm_k<false, 0><<<dim3(1, 4, 16), 256, 0, stream>>>(
        ggnn_w, pih, nullptr, wcomb, 128, 512, 128,
        (long)H * H, 65536, 65536);
    pack_b_k<<<(16 * 256 * 512 + 255) / 256, 256, 0, stream>>>(wcomb, phh, Bp);
    pack_w_k<false><<<(IN * 128 + 255) / 256, 256, 0, stream>>>(proj_w, prjHi, prjLo, IN);
    pack_w_k<false><<<(128 * 128 + 255) / 256, 256, 0, stream>>>(q_w, qwHi, qwLo, 128);
    pack_w_k<true><<<(128 * 128 + 255) / 256, 256, 0, stream>>>(k_w, kwHi, kwLo, 128);

    // ---- input projection (MFMA 3-pass) + LN + GELU ----
    gemm_mfma_k<0><<<gx64, 256, 0, stream>>>(x, prjHi, prjLo, proj_b, h0, N, IN);
    ln_gelu_k<<<rb, 256, 0, stream>>>(h0, ln0_w, ln0_b, N);

    // ---- 4 GGNN layers: gather(h) -> fused MFMA GRU ----
    float* hcur = h0;           // layer 0 reads h0 for all views (stride 0)
    for (int i = 0; i < L; i++) {
        const int* es = (i == 0) ? iEsrc0 : iEsrc;
        gather_k<<<(int)(((long)N4 * 32 + 255) / 256), 256, 0, stream>>>(
            hcur, bufY, iOff, es, N4);
        float* hnxt = (hcur == bufX) ? bufZ : bufX;   // h0 -> bufX first
        long sHc = (i == 0) ? 0 : NH;
        gemm_gru_mfma_k<<<dim3(gx64, 2, 4), 256, 0, stream>>>(
            bufY, hcur, Bp + (long)i * 131072, bp, hnxt, N, NH, sHc);
        hcur = hnxt;
    }

    // ---- per-view LN + residual (hcur becomes hs) ----
    vln_res_k<<<dim3(rb, 1, 4), 256, 0, stream>>>(hcur, h0, vln_w, vln_b, N);

    // ---- attention (MFMA) + fusion + pooling + classifier ----
    float* q = bufY;
    float* u = bufY + NH;
    float* fused = bufY + 2 * NH;
    gemm_mfma_k<1><<<gx64, 256, 0, stream>>>(h0, qwHi, qwLo, q_b, q, N, 128);
    gemm_mfma_k<0><<<gx64, 256, 0, stream>>>(q, kwHi, kwLo, nullptr, u, N, 128);
    fusion_k<<<rb, 256, 0, stream>>>(hcur, q, u, k_b, fused, N);
    pool_k<<<64, 256, 0, stream>>>(fused, batch, poolMean, poolMax, N);
    classifier_k<<<64, 256, 0, stream>>>(
        poolMean, poolMax, c1w, c1b, c2w, c2b, c3w, c3b, out);
}

// Round 6
// 1644.913 us; speedup vs baseline: 5.1677x; 1.2094x over previous
//
#include <hip/hip_runtime.h>
#include <math.h>

// ---------------------------------------------------------------------------
// MultiViewEPSSClassifier forward. N=50000, E=600000, IN=512, H=128, B=64, L=4.
// R2: atomic scatter -> CSR gather.   R3: atomic-free pooling; fused GRU GEMM.
// R4: ggnn_w folded into GRU weights; GRU GEMM -> MFMA bf16.
// R5: parallel classifier; proj/attn MFMA; bcast removed.
// R6: bf16 state pipeline: gather reads/writes bf16, GRU A single-pass bf16
//     (no in-loop conversion), fp32 h kept only for GRU epilogue (in-place);
//     XCD swizzle co-locates the y-block pair sharing A rows on one XCD.
// ---------------------------------------------------------------------------

typedef __attribute__((ext_vector_type(8))) short short8;
typedef __attribute__((ext_vector_type(4))) float floatx4;

__device__ __forceinline__ unsigned short f2bf_rtn(float x) {
    unsigned u = __float_as_uint(x);
    return (unsigned short)((u + 0x7FFFu + ((u >> 16) & 1u)) >> 16);
}
__device__ __forceinline__ float bf2f(unsigned short h) {
    return __uint_as_float((unsigned)h << 16);
}

// types {0,9,10}->0, {1,2,3}->1, {4,5,6}->2, {7,8,11,12}->3 (partition of 0..12)
__device__ __forceinline__ int view_of(int t) {
    return (t >= 1 && t <= 3) ? 1 : (t >= 4 && t <= 6) ? 2
         : ((t == 7) || (t == 8) || (t >= 11)) ? 3 : 0;
}

// ----------------- fp32 GEMM (Wcomb precompute only, tiny) -----------------
template <bool BT, int EPI>
__global__ __launch_bounds__(256, 2) void gemm_k(
    const float* __restrict__ A, const float* __restrict__ Bm,
    const float* __restrict__ bias, float* __restrict__ C,
    int N, int M, int K, long sA, long sB, long sC)
{
    __shared__ float As[32][132];
    __shared__ float Bs[32][132];
    A  += (long)blockIdx.z * sA;
    Bm += (long)blockIdx.z * sB;
    C  += (long)blockIdx.z * sC;
    const int r0 = blockIdx.x * 128;
    const int c0 = blockIdx.y * 128;
    const int tid = threadIdx.x;
    const int tx = tid & 15;
    const int ty = tid >> 4;

    float acc[8][8];
#pragma unroll
    for (int i = 0; i < 8; i++)
#pragma unroll
        for (int j = 0; j < 8; j++) acc[i][j] = 0.0f;

    for (int k0 = 0; k0 < K; k0 += 32) {
        {
            int arow = tid >> 3;
            int akq  = (tid & 7) << 2;
#pragma unroll
            for (int hh = 0; hh < 4; hh++) {
                int r  = arow + hh * 32;
                int gr = r0 + r;
                float4 av = make_float4(0.f, 0.f, 0.f, 0.f);
                if (gr < N) av = *(const float4*)(A + (long)gr * K + k0 + akq);
                As[akq + 0][r] = av.x; As[akq + 1][r] = av.y;
                As[akq + 2][r] = av.z; As[akq + 3][r] = av.w;
            }
        }
        if (BT) {
            int brow = tid >> 3;
            int bkq  = (tid & 7) << 2;
#pragma unroll
            for (int hh = 0; hh < 4; hh++) {
                int r = brow + hh * 32;
                float4 bv = *(const float4*)(Bm + (long)(c0 + r) * K + k0 + bkq);
                Bs[bkq + 0][r] = bv.x; Bs[bkq + 1][r] = bv.y;
                Bs[bkq + 2][r] = bv.z; Bs[bkq + 3][r] = bv.w;
            }
        } else {
            int kk0 = tid >> 5;
            int bmq = (tid & 31) << 2;
#pragma unroll
            for (int hh = 0; hh < 4; hh++) {
                int kk = kk0 + hh * 8;
                float4 bv = *(const float4*)(Bm + (long)(k0 + kk) * M + c0 + bmq);
                *(float4*)&Bs[kk][bmq] = bv;
            }
        }
        __syncthreads();
#pragma unroll
        for (int k = 0; k < 32; k++) {
            float4 a0 = *(const float4*)&As[k][ty << 2];
            float4 a1 = *(const float4*)&As[k][64 + (ty << 2)];
            float4 b0 = *(const float4*)&Bs[k][tx << 2];
            float4 b1 = *(const float4*)&Bs[k][64 + (tx << 2)];
            float av[8] = {a0.x, a0.y, a0.z, a0.w, a1.x, a1.y, a1.z, a1.w};
            float bv[8] = {b0.x, b0.y, b0.z, b0.w, b1.x, b1.y, b1.z, b1.w};
#pragma unroll
            for (int i = 0; i < 8; i++)
#pragma unroll
                for (int j = 0; j < 8; j++) acc[i][j] += av[i] * bv[j];
        }
        __syncthreads();
    }

    float bb[8] = {0, 0, 0, 0, 0, 0, 0, 0};
    if (bias) {
        float4 b0 = *(const float4*)(bias + c0 + (tx << 2));
        float4 b1 = *(const float4*)(bias + c0 + 64 + (tx << 2));
        bb[0] = b0.x; bb[1] = b0.y; bb[2] = b0.z; bb[3] = b0.w;
        bb[4] = b1.x; bb[5] = b1.y; bb[6] = b1.z; bb[7] = b1.w;
    }
#pragma unroll
    for (int i = 0; i < 8; i++) {
        int r = (i < 4) ? (r0 + (ty << 2) + i) : (r0 + 64 + (ty << 2) + i - 4);
        if (r < N) {
            float v[8];
#pragma unroll
            for (int j = 0; j < 8; j++) {
                v[j] = acc[i][j] + bb[j];
                if (EPI == 1) v[j] = tanhf(v[j]);
            }
            *(float4*)(C + (long)r * M + c0 + (tx << 2)) = make_float4(v[0], v[1], v[2], v[3]);
            *(float4*)(C + (long)r * M + c0 + 64 + (tx << 2)) = make_float4(v[4], v[5], v[6], v[7]);
        }
    }
}

// ---------- build P_ih_rep[16][128][512], P_hh[4][128][512], bias ----------
__global__ __launch_bounds__(256) void build_p_k(
    const float* __restrict__ gwih, const float* __restrict__ gwhh,
    const float* __restrict__ gbih, const float* __restrict__ gbhh,
    float* __restrict__ pih, float* __restrict__ phh, float* __restrict__ bp)
{
    int idx = blockIdx.x * 256 + threadIdx.x;
    if (idx < 16 * 65536) {
        int z = idx >> 16, rem = idx & 65535;
        int k = rem >> 9, mcol = rem & 511;
        int ch = mcol >> 2, g = mcol & 3;
        int v = z >> 2;
        const float* Wih = gwih + (long)v * 384 * 128;
        float val = 0.0f;
        if (g == 0) val = Wih[ch * 128 + k];
        else if (g == 1) val = Wih[(128 + ch) * 128 + k];
        else if (g == 2) val = Wih[(256 + ch) * 128 + k];
        pih[idx] = val;
    }
    if (idx < 4 * 65536) {
        int v = idx >> 16, rem = idx & 65535;
        int k = rem >> 9, mcol = rem & 511;
        int ch = mcol >> 2, g = mcol & 3;
        const float* Whh = gwhh + (long)v * 384 * 128;
        float val = 0.0f;
        if (g == 0) val = Whh[ch * 128 + k];
        else if (g == 1) val = Whh[(128 + ch) * 128 + k];
        else if (g == 3) val = Whh[(256 + ch) * 128 + k];
        phh[idx] = val;
    }
    if (idx < 4 * 512) {
        int v = idx >> 9, mcol = idx & 511;
        int ch = mcol >> 2, g = mcol & 3;
        float val;
        if (g == 0) val = gbih[v * 384 + ch] + gbhh[v * 384 + ch];
        else if (g == 1) val = gbih[v * 384 + 128 + ch] + gbhh[v * 384 + 128 + ch];
        else if (g == 2) val = gbih[v * 384 + 256 + ch];
        else val = gbhh[v * 384 + 256 + ch];
        bp[idx] = val;
    }
}

// ---- pack combined GRU weights -> bf16 frag order [z][ks][col][q*8+j] -----
__global__ __launch_bounds__(256) void pack_b_k(
    const float* __restrict__ wcomb, const float* __restrict__ phh,
    short* __restrict__ Bp)
{
    int idx = blockIdx.x * 256 + threadIdx.x;
    if (idx >= 16 * 256 * 512) return;
    int z = idx >> 17, rem = idx & 131071;
    int k = rem >> 9, col = rem & 511;
    float val = (k < 128) ? wcomb[(long)z * 65536 + k * 512 + col]
                          : phh[(long)(z >> 2) * 65536 + (k - 128) * 512 + col];
    long dst = ((long)(z * 8 + (k >> 5)) * 512 + col) * 32 + ((k >> 3) & 3) * 8 + (k & 7);
    Bp[dst] = (short)f2bf_rtn(val);
}

// ---- pack fp32 weight [K][128] (or transposed [128][K]) -> bf16 hi/lo -----
template <bool BT>
__global__ __launch_bounds__(256) void pack_w_k(
    const float* __restrict__ W, short* __restrict__ bhi, short* __restrict__ blo, int K)
{
    int idx = blockIdx.x * 256 + threadIdx.x;
    if (idx >= K * 128) return;
    int k = idx >> 7, col = idx & 127;
    float v = BT ? W[col * K + k] : W[k * 128 + col];
    unsigned short h = f2bf_rtn(v);
    float fh = __uint_as_float((unsigned)h << 16);
    long dst = ((long)(k >> 5) * 128 + col) * 32 + ((k >> 3) & 3) * 8 + (k & 7);
    bhi[dst] = (short)h;
    blo[dst] = (short)f2bf_rtn(v - fh);
}

// ------------- MFMA GEMM: C[N,128] = A[N,K]@W + bias, 3-pass ---------------
template <int EPI>
__global__ __launch_bounds__(256, 4) void gemm_mfma_k(
    const float* __restrict__ A, const short* __restrict__ Bhi,
    const short* __restrict__ Blo, const float* __restrict__ bias,
    float* __restrict__ C, int N, int K)
{
    __shared__ __align__(16) short Ahi[64 * 40];
    __shared__ __align__(16) short Alo[64 * 40];
    const int r0 = blockIdx.x * 64;
    const int tid = threadIdx.x;
    const int l = tid & 63, w = tid >> 6;
    const int wrow = w * 16;
    const int m = l & 15, q = l >> 4;

    floatx4 acc[8];
#pragma unroll
    for (int b = 0; b < 8; b++) acc[b] = (floatx4)0.0f;

    const int arow = tid >> 2;
    const int fcol = (tid & 3) * 8;
    const int gr = r0 + arow;
    const int nks = K >> 5;

    for (int ks = 0; ks < nks; ks++) {
        float xv[8];
        if (gr < N) {
            float4 x0 = *(const float4*)(A + (long)gr * K + ks * 32 + fcol);
            float4 x1 = *(const float4*)(A + (long)gr * K + ks * 32 + fcol + 4);
            xv[0] = x0.x; xv[1] = x0.y; xv[2] = x0.z; xv[3] = x0.w;
            xv[4] = x1.x; xv[5] = x1.y; xv[6] = x1.z; xv[7] = x1.w;
        } else {
#pragma unroll
            for (int u = 0; u < 8; u++) xv[u] = 0.0f;
        }
        short8 vhi, vlo;
#pragma unroll
        for (int u = 0; u < 8; u++) {
            unsigned short hb = f2bf_rtn(xv[u]);
            float fh = __uint_as_float((unsigned)hb << 16);
            vhi[u] = (short)hb;
            vlo[u] = (short)f2bf_rtn(xv[u] - fh);
        }
        *(short8*)&Ahi[arow * 40 + fcol] = vhi;
        *(short8*)&Alo[arow * 40 + fcol] = vlo;
        __syncthreads();
        short8 ah = *(short8*)&Ahi[(wrow + m) * 40 + q * 8];
        short8 al = *(short8*)&Alo[(wrow + m) * 40 + q * 8];
#pragma unroll
        for (int tn = 0; tn < 8; tn++) {
            int col = tn * 16 + m;
            short8 bh = *(const short8*)(Bhi + ((long)ks * 128 + col) * 32 + q * 8);
            short8 bl = *(const short8*)(Blo + ((long)ks * 128 + col) * 32 + q * 8);
            acc[tn] = __builtin_amdgcn_mfma_f32_16x16x32_bf16(ah, bh, acc[tn], 0, 0, 0);
            acc[tn] = __builtin_amdgcn_mfma_f32_16x16x32_bf16(al, bh, acc[tn], 0, 0, 0);
            acc[tn] = __builtin_amdgcn_mfma_f32_16x16x32_bf16(ah, bl, acc[tn], 0, 0, 0);
        }
        __syncthreads();
    }

#pragma unroll
    for (int tn = 0; tn < 8; tn++) {
        int col = tn * 16 + m;
        float bb = bias ? bias[col] : 0.0f;
#pragma unroll
        for (int reg = 0; reg < 4; reg++) {
            int row = r0 + wrow + q * 4 + reg;
            if (row < N) {
                float v = acc[tn][reg] + bb;
                if (EPI == 1) v = tanhf(v);
                C[(long)row * 128 + col] = v;
            }
        }
    }
}

// -------------- MFMA fused GRU GEMM: h_next = GRU(S, h_cur) ----------------
// A (bf16, single pass): rows = [S|h] bf16, staged via LDS. B pre-packed bf16.
// Grid x carries a swizzle so the two y-halves sharing A-rows land on the
// same XCD (bid%8): x=(xb&7)|((xb>>4)<<3), yhalf=(xb>>3)&1.
// Epilogue: fp32 h read in-place (same element it writes), writes fp32+bf16.
__global__ __launch_bounds__(256, 3) void gemm_gru_mfma_k(
    const short* __restrict__ Sb, const short* __restrict__ hb,
    const float* __restrict__ hpf, const short* __restrict__ Bp,
    const float* __restrict__ bp, float* __restrict__ hf,
    short* __restrict__ hbn, int N, long sV, long sHb, long sHp)
{
    __shared__ __align__(16) short As[64 * 40];
    const int xb = blockIdx.x;
    const int x = (xb & 7) | ((xb >> 4) << 3);
    const int yb = (xb >> 3) & 1;
    if (x * 64 >= N) return;
    const int z = blockIdx.z;
    Sb  += (long)z * sV;
    hb  += (long)z * sHb;
    hpf += (long)z * sHp;
    Bp  += (long)z * 524288;
    bp  += (long)z * 512;
    hf  += (long)z * sV;
    hbn += (long)z * sV;
    const int r0  = x * 64;
    const int c0b = yb * 256;
    const int tid = threadIdx.x;
    const int l = tid & 63, w = tid >> 6;
    const int wrow = (w & 1) * 32, wcol = (w >> 1) * 128;
    const int m = l & 15, q = l >> 4;

    floatx4 acc[2][8];
#pragma unroll
    for (int a = 0; a < 2; a++)
#pragma unroll
        for (int b = 0; b < 8; b++) acc[a][b] = (floatx4)0.0f;

    const int arow = tid >> 2;
    const int fcol = (tid & 3) * 8;
    const int gr = r0 + arow;

    for (int ks = 0; ks < 8; ks++) {
        const short* asrc = (ks < 4) ? Sb : hb;
        const int koff = (ks & 3) * 32 + fcol;
        short8 av = (short8)0;
        if (gr < N) av = *(const short8*)(asrc + (long)gr * 128 + koff);
        short8 bfr[8];
#pragma unroll
        for (int tn = 0; tn < 8; tn++) {
            int col = c0b + wcol + tn * 16 + m;
            bfr[tn] = *(const short8*)(Bp + ((long)ks * 512 + col) * 32 + q * 8);
        }
        *(short8*)&As[arow * 40 + fcol] = av;
        __syncthreads();
        short8 a0 = *(short8*)&As[(wrow + m) * 40 + q * 8];
        short8 a1 = *(short8*)&As[(wrow + 16 + m) * 40 + q * 8];
#pragma unroll
        for (int tn = 0; tn < 8; tn++) {
            acc[0][tn] = __builtin_amdgcn_mfma_f32_16x16x32_bf16(a0, bfr[tn], acc[0][tn], 0, 0, 0);
            acc[1][tn] = __builtin_amdgcn_mfma_f32_16x16x32_bf16(a1, bfr[tn], acc[1][tn], 0, 0, 0);
        }
        __syncthreads();
    }

    // ---- GRU epilogue: quad (4 gate cols) -> per-lane row via shuffles ----
    const int g = l & 3;
    const int q0 = l & ~3;
#pragma unroll
    for (int tm = 0; tm < 2; tm++) {
        const int row = r0 + wrow + tm * 16 + q * 4 + g;
#pragma unroll
        for (int tn = 0; tn < 8; tn++) {
            floatx4 a = acc[tm][tn];
            float vr = 0.f, vz = 0.f, vn = 0.f, vh = 0.f;
#pragma unroll
            for (int i = 0; i < 4; i++) {
                float t0 = __shfl(a[i], q0 + 0);
                float t1 = __shfl(a[i], q0 + 1);
                float t2 = __shfl(a[i], q0 + 2);
                float t3 = __shfl(a[i], q0 + 3);
                if (g == i) { vr = t0; vz = t1; vn = t2; vh = t3; }
            }
            const int colq = c0b + wcol + tn * 16 + (m & ~3);
            if (row < N) {
                float4 bv = *(const float4*)(bp + colq);
                int ch = colq >> 2;
                float hp = hpf[(long)row * 128 + ch];
                float rr = 1.0f / (1.0f + expf(-(vr + bv.x)));
                float zz = 1.0f / (1.0f + expf(-(vz + bv.y)));
                float nn = tanhf(vn + bv.z + rr * (vh + bv.w));
                float hnv = (1.0f - zz) * nn + zz * hp;
                hf[(long)row * 128 + ch] = hnv;
                hbn[(long)row * 128 + ch] = (short)f2bf_rtn(hnv);
            }
        }
    }
}

// ------------- LayerNorm + GELU (in-place) + bf16 copy out -----------------
__global__ __launch_bounds__(256) void ln_gelu_k(
    float* __restrict__ h0, short* __restrict__ h0b,
    const float* __restrict__ w, const float* __restrict__ b, int N)
{
    long t = (long)blockIdx.x * 256 + threadIdx.x;
    int n = (int)(t >> 5), lane = (int)(t & 31);
    if (n >= N) return;
    float* p = h0 + (long)n * 128 + lane * 4;
    float4 x = *(float4*)p;
    float s = x.x + x.y + x.z + x.w;
#pragma unroll
    for (int off = 16; off >= 1; off >>= 1) s += __shfl_xor(s, off);
    float mu = s * (1.0f / 128.0f);
    float4 d = make_float4(x.x - mu, x.y - mu, x.z - mu, x.w - mu);
    float ss = d.x * d.x + d.y * d.y + d.z * d.z + d.w * d.w;
#pragma unroll
    for (int off = 16; off >= 1; off >>= 1) ss += __shfl_xor(ss, off);
    float inv = 1.0f / sqrtf(ss * (1.0f / 128.0f) + 1e-5f);
    float4 wv = *(const float4*)(w + lane * 4);
    float4 bv = *(const float4*)(b + lane * 4);
    float y[4] = {d.x * inv * wv.x + bv.x, d.y * inv * wv.y + bv.y,
                  d.z * inv * wv.z + bv.z, d.w * inv * wv.w + bv.w};
#pragma unroll
    for (int i = 0; i < 4; i++)
        y[i] = 0.5f * y[i] * (1.0f + erff(y[i] * 0.70710678118654752f));
    *(float4*)p = make_float4(y[0], y[1], y[2], y[3]);
    ushort4 hb;
    hb.x = f2bf_rtn(y[0]); hb.y = f2bf_rtn(y[1]);
    hb.z = f2bf_rtn(y[2]); hb.w = f2bf_rtn(y[3]);
    *(ushort4*)(h0b + (long)n * 128 + lane * 4) = hb;
}

// ------------------------------ CSR build ----------------------------------
__global__ __launch_bounds__(256) void count_k(
    const int* __restrict__ dst, const int* __restrict__ et,
    int* __restrict__ cnt, int E, int N)
{
    int e = blockIdx.x * 256 + threadIdx.x;
    if (e >= E) return;
    int v = view_of(et[e]);
    atomicAdd(&cnt[v * N + dst[e]], 1);
}

__global__ __launch_bounds__(256) void scan1_k(
    const int* __restrict__ cnt, int* __restrict__ off, int* __restrict__ bsum, int n)
{
    __shared__ int sm[256];
    int base = blockIdx.x * 1024;
    int tid = threadIdx.x;
    int v[4]; int s = 0;
#pragma unroll
    for (int i = 0; i < 4; i++) {
        int idx = base + tid * 4 + i;
        v[i] = (idx < n) ? cnt[idx] : 0; s += v[i];
    }
    sm[tid] = s; __syncthreads();
    for (int o = 1; o < 256; o <<= 1) {
        int t2 = (tid >= o) ? sm[tid - o] : 0;
        __syncthreads(); sm[tid] += t2; __syncthreads();
    }
    int run = sm[tid] - s;
    if (tid == 255) bsum[blockIdx.x] = sm[255];
#pragma unroll
    for (int i = 0; i < 4; i++) {
        int idx = base + tid * 4 + i;
        if (idx < n) off[idx] = run;
        run += v[i];
    }
}

__global__ __launch_bounds__(256) void scan2_k(int* __restrict__ bsum, int nb)
{
    __shared__ int sm[256];
    int tid = threadIdx.x;
    int v = (tid < nb) ? bsum[tid] : 0;
    sm[tid] = v; __syncthreads();
    for (int o = 1; o < 256; o <<= 1) {
        int t2 = (tid >= o) ? sm[tid - o] : 0;
        __syncthreads(); sm[tid] += t2; __syncthreads();
    }
    if (tid < nb) bsum[tid] = sm[tid] - v;
}

__global__ __launch_bounds__(256) void scan3_k(
    int* __restrict__ off, int* __restrict__ cursor,
    const int* __restrict__ bsum, int n, int total)
{
    int i = blockIdx.x * 256 + threadIdx.x;
    if (i < n) {
        int o = off[i] + bsum[i >> 10];
        off[i] = o; cursor[i] = o;
    }
    if (i == 0) off[n] = total;
}

__global__ __launch_bounds__(256) void fill_k(
    const int* __restrict__ src, const int* __restrict__ dst,
    const int* __restrict__ et, int* __restrict__ cursor,
    int* __restrict__ esrc, int* __restrict__ esrc0, int E, int N)
{
    int e = blockIdx.x * 256 + threadIdx.x;
    if (e >= E) return;
    int v = view_of(et[e]);
    int b = v * N + dst[e];
    int pos = atomicAdd(&cursor[b], 1);
    esrc[pos] = v * N + src[e];
    esrc0[pos] = src[e];
}

// ---------------- CSR gather (bf16 in/out): S[r] = sum h[esrc[j]] ----------
__global__ __launch_bounds__(256) void gather_bf_k(
    const short* __restrict__ hb, short* __restrict__ Sb,
    const int* __restrict__ off, const int* __restrict__ esrc, int R)
{
    long t = (long)blockIdx.x * 256 + threadIdx.x;
    int r = (int)(t >> 5), lane = (int)(t & 31);
    if (r >= R) return;
    int beg = off[r], end = off[r + 1];
    float a0 = 0.f, a1 = 0.f, a2 = 0.f, a3 = 0.f;
    for (int j = beg; j < end; j++) {
        int s = esrc[j];
        ushort4 v = *(const ushort4*)(hb + (long)s * 128 + lane * 4);
        a0 += bf2f(v.x); a1 += bf2f(v.y); a2 += bf2f(v.z); a3 += bf2f(v.w);
    }
    ushort4 o;
    o.x = f2bf_rtn(a0); o.y = f2bf_rtn(a1);
    o.z = f2bf_rtn(a2); o.w = f2bf_rtn(a3);
    *(ushort4*)(Sb + (long)r * 128 + lane * 4) = o;
}

// -------------------- per-view LayerNorm + residual (in-place) -------------
__global__ __launch_bounds__(256) void vln_res_k(
    float* __restrict__ h, const float* __restrict__ h0,
    const float* __restrict__ w, const float* __restrict__ b, int N)
{
    int v = blockIdx.z;
    long t = (long)blockIdx.x * 256 + threadIdx.x;
    int n = (int)(t >> 5), lane = (int)(t & 31);
    if (n >= N) return;
    float* hp = h + ((long)v * N + n) * 128 + lane * 4;
    float4 x = *(float4*)hp;
    float s = x.x + x.y + x.z + x.w;
#pragma unroll
    for (int off = 16; off >= 1; off >>= 1) s += __shfl_xor(s, off);
    float mu = s * (1.0f / 128.0f);
    float4 d = make_float4(x.x - mu, x.y - mu, x.z - mu, x.w - mu);
    float ss = d.x * d.x + d.y * d.y + d.z * d.z + d.w * d.w;
#pragma unroll
    for (int off = 16; off >= 1; off >>= 1) ss += __shfl_xor(ss, off);
    float inv = 1.0f / sqrtf(ss * (1.0f / 128.0f) + 1e-5f);
    float4 wv = *(const float4*)(w + v * 128 + lane * 4);
    float4 bv = *(const float4*)(b + v * 128 + lane * 4);
    float4 hv = *(const float4*)(h0 + (long)n * 128 + lane * 4);
    float4 r;
    r.x = d.x * inv * wv.x + bv.x + hv.x;
    r.y = d.y * inv * wv.y + bv.y + hv.y;
    r.z = d.z * inv * wv.z + bv.z + hv.z;
    r.w = d.w * inv * wv.w + bv.w + hv.w;
    *(float4*)hp = r;
}

// -------------- attention fusion (no atomics): fused[N,128] ----------------
__global__ __launch_bounds__(256) void fusion_k(
    const float* __restrict__ hs, const float* __restrict__ q,
    const float* __restrict__ u, const float* __restrict__ kb,
    float* __restrict__ fused, int N)
{
    long t = (long)blockIdx.x * 256 + threadIdx.x;
    int n = (int)(t >> 5), lane = (int)(t & 31);
    if (n >= N) return;
    long NH = (long)N * 128;
    float4 qv = *(const float4*)(q + (long)n * 128 + lane * 4);
    float4 kv = *(const float4*)(kb + lane * 4);
    float4 uv = *(const float4*)(u + (long)n * 128 + lane * 4);
    float part = qv.x * kv.x + qv.y * kv.y + qv.z * kv.z + qv.w * kv.w;
    float4 hv[4];
    float lg[4];
#pragma unroll
    for (int v = 0; v < 4; v++) {
        hv[v] = *(const float4*)(hs + v * NH + (long)n * 128 + lane * 4);
        lg[v] = hv[v].x * uv.x + hv[v].y * uv.y + hv[v].z * uv.z + hv[v].w * uv.w;
    }
#pragma unroll
    for (int off = 16; off >= 1; off >>= 1) {
        part += __shfl_xor(part, off);
#pragma unroll
        for (int v = 0; v < 4; v++) lg[v] += __shfl_xor(lg[v], off);
    }
    const float scale = 0.08838834764831845f;
    float mx = -1e30f;
#pragma unroll
    for (int v = 0; v < 4; v++) { lg[v] = (lg[v] + part) * scale; mx = fmaxf(mx, lg[v]); }
    float se = 0.0f;
#pragma unroll
    for (int v = 0; v < 4; v++) { lg[v] = expf(lg[v] - mx); se += lg[v]; }
    float inv = 1.0f / se;
    float4 f = make_float4(0.f, 0.f, 0.f, 0.f);
#pragma unroll
    for (int v = 0; v < 4; v++) {
        float a = lg[v] * inv;
        f.x += a * hv[v].x; f.y += a * hv[v].y; f.z += a * hv[v].z; f.w += a * hv[v].w;
    }
    *(float4*)(fused + (long)n * 128 + lane * 4) = f;
}

// ------------- pooling: one block per graph (batch is sorted) --------------
__global__ __launch_bounds__(256) void pool_k(
    const float* __restrict__ fused, const int* __restrict__ batch,
    float* __restrict__ meanb, float* __restrict__ maxb, int N)
{
    __shared__ float s_sum[256], s_max[256];
    int b = blockIdx.x;
    int lo = 0, hi = N;
    while (lo < hi) { int mid = (lo + hi) >> 1; if (batch[mid] < b) lo = mid + 1; else hi = mid; }
    int beg = lo;
    lo = beg; hi = N;
    while (lo < hi) { int mid = (lo + hi) >> 1; if (batch[mid] < b + 1) lo = mid + 1; else hi = mid; }
    int end = lo;
    int tid = threadIdx.x;
    int c = tid & 127, half = tid >> 7;
    float sum = 0.0f, mx = __int_as_float(0xff800000);
    for (int n = beg + half; n < end; n += 2) {
        float v = fused[(long)n * 128 + c];
        sum += v; mx = fmaxf(mx, v);
    }
    s_sum[tid] = sum; s_max[tid] = mx;
    __syncthreads();
    if (half == 0) {
        float tot = s_sum[tid] + s_sum[tid + 128];
        float m2 = fmaxf(s_max[tid], s_max[tid + 128]);
        int cnt = end - beg;
        meanb[b * 128 + c] = tot / (float)max(cnt, 1);
        maxb[b * 128 + c] = m2;
    }
}

// ---------------- classifier MLP: one block per graph (64 blocks) ----------
__global__ __launch_bounds__(256) void classifier_k(
    const float* __restrict__ meanb, const float* __restrict__ maxb,
    const float* __restrict__ c1w, const float* __restrict__ c1b,
    const float* __restrict__ c2w, const float* __restrict__ c2b,
    const float* __restrict__ c3w, const float* __restrict__ c3b,
    float* __restrict__ out)
{
    __shared__ float g[256];
    __shared__ float h1[128];
    __shared__ float h2[64];
    int b = blockIdx.x, tid = threadIdx.x;
    g[tid] = (tid < 128) ? meanb[b * 128 + tid] : maxb[b * 128 + (tid - 128)];
    __syncthreads();
    if (tid < 128) {
        float acc = c1b[tid];
        for (int k = 0; k < 256; k++) acc += g[k] * c1w[k * 128 + tid];
        h1[tid] = fmaxf(acc, 0.0f);
    }
    __syncthreads();
    if (tid < 64) {
        float acc = c2b[tid];
        for (int k = 0; k < 128; k++) acc += h1[k] * c2w[k * 64 + tid];
        h2[tid] = fmaxf(acc, 0.0f);
    }
    __syncthreads();
    if (tid < 64) {
        float p = h2[tid] * c3w[tid];
#pragma unroll
        for (int off = 32; off >= 1; off >>= 1) p += __shfl_xor(p, off);
        if (tid == 0) out[b] = c3b[0] + p;
    }
}

// ---------------------------------------------------------------------------
extern "C" void kernel_launch(void* const* d_in, const int* in_sizes, int n_in,
                              void* d_out, int out_size, void* d_ws, size_t ws_size,
                              hipStream_t stream) {
    (void)n_in; (void)out_size; (void)ws_size;
    const float* x      = (const float*)d_in[0];
    const int*   eidx   = (const int*)d_in[1];
    const int*   etype  = (const int*)d_in[2];
    const int*   batch  = (const int*)d_in[3];
    const float* proj_w = (const float*)d_in[4];
    const float* proj_b = (const float*)d_in[5];
    const float* ln0_w  = (const float*)d_in[6];
    const float* ln0_b  = (const float*)d_in[7];
    const float* ggnn_w = (const float*)d_in[8];
    const float* gwih   = (const float*)d_in[9];
    const float* gwhh   = (const float*)d_in[10];
    const float* gbih   = (const float*)d_in[11];
    const float* gbhh   = (const float*)d_in[12];
    const float* vln_w  = (const float*)d_in[13];
    const float* vln_b  = (const float*)d_in[14];
    const float* q_w    = (const float*)d_in[15];
    const float* q_b    = (const float*)d_in[16];
    const float* k_w    = (const float*)d_in[17];
    const float* k_b    = (const float*)d_in[18];
    const float* c1w    = (const float*)d_in[19];
    const float* c1b    = (const float*)d_in[20];
    const float* c2w    = (const float*)d_in[21];
    const float* c2b    = (const float*)d_in[22];
    const float* c3w    = (const float*)d_in[23];
    const float* c3b    = (const float*)d_in[24];
    float* out = (float*)d_out;

    const int N = in_sizes[3];
    const int E = in_sizes[2];
    const int IN = in_sizes[0] / N;
    const int H = 128, L = 4;
    const int N4 = 4 * N;

    long NH = (long)N * H;
    float* ws = (float*)d_ws;
    float* h0 = ws;                      // NH
    float* hf = h0 + NH;                 // 4*NH  (fp32 h, in-place across layers)
    float* poolMean = hf + 4 * NH;       // 8192
    float* poolMax  = poolMean + 8192;   // 8192
    float* bp = poolMax + 8192;          // 2048
    short* h0b = (short*)(bp + 2048);    // NH
    short* hbA = h0b + NH;               // 4*NH
    short* hbB = hbA + 4 * NH;           // 4*NH
    short* Sb  = hbB + 4 * NH;           // 4*NH
    short* Bp  = Sb + 4 * NH;            // 16*131072
    short* prjHi = Bp + 16 * 131072;     // 512*128
    short* prjLo = prjHi + 65536;
    short* qwHi  = prjLo + 65536;        // 128*128
    short* qwLo  = qwHi + 16384;
    short* kwHi  = qwLo + 16384;
    short* kwLo  = kwHi + 16384;
    int* iOff  = (int*)(kwLo + 16384);   // N4+1
    int* iCnt  = iOff + N4 + 1;
    int* iCur  = iCnt + N4;
    int* iBsum = iCur + N4;              // 256
    int* iEsrc  = iBsum + 256;           // E
    int* iEsrc0 = iEsrc + E;             // E
    // precompute overlays on hf (dead before layer 0 writes hf)
    float* wcomb = hf;                   // 16*65536
    float* pih   = hf + 16 * 65536;      // 16*65536
    float* phh   = pih + 16 * 65536;     // 4*65536
    // tail overlays (dead after last GRU)
    float* qbuf  = (float*)Sb;           // NH
    float* ubuf  = qbuf + NH;            // NH
    float* fused = (float*)hbA;          // NH

    int rb = (int)(((long)N * 32 + 255) / 256);
    int eb = (E + 255) / 256;
    int nbScan = (N4 + 1023) / 1024;
    int gx64 = (N + 63) / 64;
    int gxp = ((gx64 + 7) / 8) * 8;

    const int* esrc_in = eidx;
    const int* edst_in = eidx + E;

    // ---- CSR build ----
    hipMemsetAsync(iCnt, 0, (size_t)N4 * sizeof(int), stream);
    count_k<<<eb, 256, 0, stream>>>(edst_in, etype, iCnt, E, N);
    scan1_k<<<nbScan, 256, 0, stream>>>(iCnt, iOff, iBsum, N4);
    scan2_k<<<1, 256, 0, stream>>>(iBsum, nbScan);
    scan3_k<<<(N4 + 255) / 256, 256, 0, stream>>>(iOff, iCur, iBsum, N4, E);
    fill_k<<<eb, 256, 0, stream>>>(esrc_in, edst_in, etype, iCur, iEsrc, iEsrc0, E, N);

    // ---- GRU weight fold + bf16 packs (once per call) ----
    build_p_k<<<(16 * 65536 + 255) / 256, 256, 0, stream>>>(
        gwih, gwhh, gbih, gbhh, pih, phh, bp);
    gemm_k<false, 0><<<dim3(1, 4, 16), 256, 0, stream>>>(
        ggnn_w, pih, nullptr, wcomb, 128, 512, 128,
        (long)H * H, 65536, 65536);
    pack_b_k<<<(16 * 256 * 512 + 255) / 256, 256, 0, stream>>>(wcomb, phh, Bp);
    pack_w_k<false><<<(IN * 128 + 255) / 256, 256, 0, stream>>>(proj_w, prjHi, prjLo, IN);
    pack_w_k<false><<<(128 * 128 + 255) / 256, 256, 0, stream>>>(q_w, qwHi, qwLo, 128);
    pack_w_k<true><<<(128 * 128 + 255) / 256, 256, 0, stream>>>(k_w, kwHi, kwLo, 128);

    // ---- input projection (MFMA 3-pass) + LN + GELU (+bf16 copy) ----
    gemm_mfma_k<0><<<gx64, 256, 0, stream>>>(x, prjHi, prjLo, proj_b, h0, N, IN);
    ln_gelu_k<<<rb, 256, 0, stream>>>(h0, h0b, ln0_w, ln0_b, N);

    // ---- 4 GGNN layers: bf16 gather -> single-pass MFMA GRU ----
    const float* hpf = h0;   long sHp = 0;
    const short* hbc = h0b;  long sHb = 0;
    short* hbn = hbA;
    for (int i = 0; i < L; i++) {
        const int* es = (i == 0) ? iEsrc0 : iEsrc;
        gather_bf_k<<<(int)(((long)N4 * 32 + 255) / 256), 256, 0, stream>>>(
            hbc, Sb, iOff, es, N4);
        gemm_gru_mfma_k<<<dim3(2 * gxp, 1, 4), 256, 0, stream>>>(
            Sb, hbc, hpf, Bp + (long)i * 131072, bp, hf, hbn, N, NH, sHb, sHp);
        hpf = hf; sHp = NH;
        hbc = hbn; sHb = NH;
        hbn = (hbn == hbA) ? hbB : hbA;
    }

    // ---- per-view LN + residual (hf becomes hs) ----
    vln_res_k<<<dim3(rb, 1, 4), 256, 0, stream>>>(hf, h0, vln_w, vln_b, N);

    // ---- attention (MFMA) + fusion + pooling + classifier ----
    gemm_mfma_k<1><<<gx64, 256, 0, stream>>>(h0, qwHi, qwLo, q_b, qbuf, N, 128);
    gemm_mfma_k<0><<<gx64, 256, 0, stream>>>(qbuf, kwHi, kwLo, nullptr, ubuf, N, 128);
    fusion_k<<<rb, 256, 0, stream>>>(hf, qbuf, ubuf, k_b, fused, N);
    pool_k<<<64, 256, 0, stream>>>(fused, batch, poolMean, poolMax, N);
    classifier_k<<<64, 256, 0, stream>>>(
        poolMean, poolMax, c1w, c1b, c2w, c2b, c3w, c3b, out);
}